// Round 16
// baseline (309.308 us; speedup 1.0000x reference)
//
#include <hip/hip_runtime.h>
#include <math.h>

#define NB   4
#define NH   16
#define SLQ  1024
#define SLK  2048
#define DM   1024
#define HD   64

typedef __attribute__((ext_vector_type(8))) short s16x8;
typedef __attribute__((ext_vector_type(4))) short s16x4;
typedef __attribute__((ext_vector_type(4))) float f32x4;
typedef unsigned short u16;
typedef unsigned int   u32;

#if defined(__has_builtin)
#if __has_builtin(__builtin_amdgcn_exp2f)
#define EXP2(x) __builtin_amdgcn_exp2f(x)
#else
#define EXP2(x) exp2f(x)
#endif
#else
#define EXP2(x) exp2f(x)
#endif

// 0.125 * log2(e): scores scaled to base-2 inside attn/wmean
#define C2 0.18033688011116012f

__device__ inline u16 f2bf(float f) {
  u32 u = __float_as_uint(f);
  u32 r = u + 0x7fffu + ((u >> 16) & 1u);
  return (u16)(r >> 16);
}
__device__ inline float bf2f(u16 h) { return __uint_as_float(((u32)h) << 16); }

// pack 2 f32 -> 2 bf16 (RNE), lo = a, hi = b
__device__ __forceinline__ u32 cvtpk(float a, float b) {
  u32 r;
  asm("v_cvt_pk_bf16_f32 %0, %1, %2" : "=v"(r) : "v"(a), "v"(b));
  return r;
}

// async global->LDS, 16B per lane; LDS dest must be wave-uniform base.
__device__ __forceinline__ void gl16(const void* g, void* l) {
  __builtin_amdgcn_global_load_lds(
      (const __attribute__((address_space(1))) unsigned int*)g,
      (__attribute__((address_space(3))) unsigned int*)l, 16, 0, 0);
}

// ---------------------------------------------------------------------------
// prep_k: fused setup, one launch, 2048 blocks by range:
//   [0,256)     mask -> bitmask (ballot, grid-stride)
//   [256,1024)  f32 -> bf16 for mq and reply (768 blocks, grid-stride)
//   [1024,2048) 4x W[1024][1024] -> WT[n][k] bf16 (tile per block)
// ---------------------------------------------------------------------------
__global__ __launch_bounds__(256) void prep_k(
    const int* __restrict__ mask, unsigned long long* __restrict__ bits,
    const float* __restrict__ mq, u16* __restrict__ mqb,
    const float* __restrict__ reply, u16* __restrict__ rpb,
    const float* __restrict__ W0, const float* __restrict__ W1,
    const float* __restrict__ W2, const float* __restrict__ W3,
    u16* __restrict__ T0, u16* __restrict__ T1,
    u16* __restrict__ T2, u16* __restrict__ T3) {
  __shared__ float ts[64][68];
  const int gid = blockIdx.x, t = threadIdx.x;
  if (gid < 256) {
    const int nwords = NB*SLQ*SLK/64;
    int gw   = (gid * 256 + t) >> 6;
    int lane = t & 63;
    const int nw = (256 * 256) >> 6;   // 1024 waves
    for (int w = gw; w < nwords; w += nw) {
      int m = mask[(size_t)w * 64 + lane];
      unsigned long long b = __ballot(m != 0);
      if (lane == 0) bits[w] = b;
    }
  } else if (gid < 1024) {
    const int g = gid - 256;
    const int na = NB*SLQ*DM, nb = NB*SLK*DM;
    const int stride = 768 * 256 * 8;
    for (int i = (g * 256 + t) * 8; i < na + nb; i += stride) {
      const float* s; u16* d; int off;
      if (i < na) { s = mq; d = mqb; off = i; } else { s = reply; d = rpb; off = i - na; }
      float4 x = *(const float4*)(s + off);
      float4 y = *(const float4*)(s + off + 4);
      s16x8 o;
      o[0] = (short)f2bf(x.x); o[1] = (short)f2bf(x.y);
      o[2] = (short)f2bf(x.z); o[3] = (short)f2bf(x.w);
      o[4] = (short)f2bf(y.x); o[5] = (short)f2bf(y.y);
      o[6] = (short)f2bf(y.z); o[7] = (short)f2bf(y.w);
      *(s16x8*)(d + off) = o;
    }
  } else {
    const int g = gid - 1024;
    const int cx = g & 15, ry = (g >> 4) & 15, wz = g >> 8;
    const float* W; u16* T;
    switch (wz) {
      case 0:  W = W0; T = T0; break;
      case 1:  W = W1; T = T1; break;
      case 2:  W = W2; T = T2; break;
      default: W = W3; T = T3; break;
    }
    const int r0 = ry * 64, c0 = cx * 64;
    const int rr = t >> 4, cc = t & 15;
#pragma unroll
    for (int p = 0; p < 4; ++p) {
      float4 v = *(const float4*)(W + (size_t)(r0 + rr + p*16) * DM + c0 + cc*4);
      *(float4*)&ts[rr + p*16][cc*4] = v;
    }
    __syncthreads();
    const int c = t >> 2, ch = t & 3;
    s16x8 h0, h1;
#pragma unroll
    for (int i = 0; i < 8; ++i) {
      h0[i] = (short)f2bf(ts[ch*16 + i][c]);
      h1[i] = (short)f2bf(ts[ch*16 + 8 + i][c]);
    }
    size_t base = (size_t)(c0 + c) * DM + r0 + ch*16;
    *(s16x8*)(T + base) = h0; *(s16x8*)(T + base + 8) = h1;
  }
}

// ---------------------------------------------------------------------------
// Grouped projection GEMM: q (natural), k (natural), v (transposed vT).
// 1280 blocks; k/v interleaved pairs share A-tiles.
// ---------------------------------------------------------------------------
__global__ __launch_bounds__(256) void proj_gemm_k(
    const u16* __restrict__ mqb, const u16* __restrict__ rpb,
    const u16* __restrict__ WqT, const u16* __restrict__ WkT,
    const u16* __restrict__ WvT,
    const float* __restrict__ bq, const float* __restrict__ bk,
    const float* __restrict__ bv,
    u16* __restrict__ qbf, u16* __restrict__ kbf, u16* __restrict__ vTp) {
  const int gid = blockIdx.x;
  const u16* A; const u16* BT; const float* bias; u16* out;
  int mode, mt, nt;
  if (gid < 256) {
    A = mqb; BT = WqT; bias = bq; out = qbf; mode = 0;
    nt = gid & 7; mt = gid >> 3;
  } else {
    const int g = gid - 256, pair = g >> 1;
    nt = pair & 7; mt = pair >> 3;
    if ((g & 1) == 0) { A = rpb; BT = WkT; bias = bk; out = kbf; mode = 0; }
    else              { A = rpb; BT = WvT; bias = bv; out = vTp; mode = 1; }
  }
  const int m0 = mt * 128, n0 = nt * 128;

  __shared__ u16 Ah[128 * 32];
  __shared__ u16 Bh[128 * 32];
  const int t = threadIdx.x;
  const int wid = t >> 6, lane = t & 63, lg = lane >> 4, lm = lane & 15;
  const int wr = wid >> 1, wc = wid & 1;
  f32x4 acc[4][4];
#pragma unroll
  for (int i = 0; i < 4; ++i)
#pragma unroll
    for (int j = 0; j < 4; ++j) acc[i][j] = (f32x4)(0.0f);

  const int c0 = wid * 2, c1 = wid * 2 + 1;
  const int sr0 = c0 * 16 + (lane >> 2), sr1 = c1 * 16 + (lane >> 2);
  const int spc = (lane & 3) * 8;
  for (int k0 = 0; k0 < DM; k0 += 32) {
    gl16(A  + (size_t)(m0 + sr0) * DM + k0 + spc, &Ah[c0 * 512]);
    gl16(A  + (size_t)(m0 + sr1) * DM + k0 + spc, &Ah[c1 * 512]);
    gl16(BT + (size_t)(n0 + sr0) * DM + k0 + spc, &Bh[c0 * 512]);
    gl16(BT + (size_t)(n0 + sr1) * DM + k0 + spc, &Bh[c1 * 512]);
    __syncthreads();
    s16x8 ah[4], bh[4];
#pragma unroll
    for (int i = 0; i < 4; ++i) {
      ah[i] = *(const s16x8*)&Ah[(wr*64 + i*16 + lm) * 32 + lg*8];
      bh[i] = *(const s16x8*)&Bh[(wc*64 + i*16 + lm) * 32 + lg*8];
    }
#pragma unroll
    for (int i = 0; i < 4; ++i)
#pragma unroll
      for (int j = 0; j < 4; ++j)
        acc[i][j] = __builtin_amdgcn_mfma_f32_16x16x32_bf16(ah[i], bh[j], acc[i][j], 0, 0, 0);
    __syncthreads();
  }
#pragma unroll
  for (int i = 0; i < 4; ++i)
#pragma unroll
    for (int j = 0; j < 4; ++j) {
      const int colg = n0 + wc*64 + j*16 + lm;
      const int rowb = m0 + wr*64 + i*16 + lg*4;
      const float bcol = bias[colg];
      if (mode == 0) {
#pragma unroll
        for (int r = 0; r < 4; ++r)
          out[(size_t)(rowb + r) * DM + colg] = f2bf(acc[i][j][r] + bcol);
      } else {  // vT transposed bf16
        const int bb = rowb >> 11, key = rowb & 2047;
        const int hh = colg >> 6, dv = colg & 63;
        s16x4 pk;
#pragma unroll
        for (int r = 0; r < 4; ++r) pk[r] = (short)f2bf(acc[i][j][r] + bcol);
        *(s16x4*)(out + (((size_t)bb*NH + hh)*HD + dv)*SLK + key) = pk;
      }
    }
}

// ---------------------------------------------------------------------------
// Flash attention. Round-11 body, staging upgraded to global_load_lds with
// T2 both-sides swizzle (rule #21): LINEAR [64][64] LDS, inverse-swizzled
// global source piece sw = (l&7)^((l>>3)&7), swizzled read col pc0 =
// (lg^(lm&7))*8 (k-half 1 = pc0^32). Data bits identical to the padded
// layout; 4 gl16/wave replaces 4 loads + 4 ds_writes per THREAD per tile.
// ---------------------------------------------------------------------------
__global__ __launch_bounds__(256) void attn_mfma_k(
    const u16* __restrict__ qb, const u16* __restrict__ kb,
    const u16* __restrict__ vT, const u32* __restrict__ mbits,
    u16* __restrict__ wv, float* __restrict__ ml) {
  __shared__ u16 ks[64 * 64];
  __shared__ u16 vs[64 * 64];
  __shared__ u16 ps[4][16][72];
  const int qt = blockIdx.x, h = blockIdx.y, b = blockIdx.z;
  const int t = threadIdx.x, wid = t >> 6, lane = t & 63, lg = lane >> 4, lm = lane & 15;
  const int q0 = qt * 64, qw = q0 + wid * 16;
  s16x8 qh[2];
#pragma unroll
  for (int s = 0; s < 2; ++s) {
    size_t off = ((size_t)(b*SLQ + qw + lm)) * DM + h*HD + s*32 + lg*8;
    qh[s] = *(const s16x8*)(qb + off);
  }
  f32x4 O[4];
#pragma unroll
  for (int j = 0; j < 4; ++j) O[j] = (f32x4)(0.0f);
  float m_r[4] = {-INFINITY, -INFINITY, -INFINITY, -INFINITY};
  float l_r[4] = {0.f, 0.f, 0.f, 0.f};   // per-lane partials (16 lanes/row)
  // gl16 staging geometry: chunk = 1KB = 8 rows x 128B; wave stages chunks
  // {2*wid, 2*wid+1} of ks and vs. Lane covers row chunk*8+(lane>>3),
  // global 16B piece sw (inverse swizzle).
  const int sw  = ((lane & 7) ^ ((lane >> 3) & 7)) * 8;  // u16 col of source
  const int c0r = wid * 16 + (lane >> 3);                 // chunk0 row
  const int c1r = c0r + 8;                                // chunk1 row
  const int pc0 = (lg ^ (lm & 7)) * 8;                    // read col, half 0
  for (int j0 = 0; j0 < SLK; j0 += 64) {
    gl16(kb + (size_t)(b*SLK + j0 + c0r) * DM + h*HD + sw, &ks[(wid*2)   * 512]);
    gl16(kb + (size_t)(b*SLK + j0 + c1r) * DM + h*HD + sw, &ks[(wid*2+1) * 512]);
    gl16(vT + ((size_t)(b*NH + h)*HD + c0r) * SLK + j0 + sw, &vs[(wid*2)   * 512]);
    gl16(vT + ((size_t)(b*NH + h)*HD + c1r) * SLK + j0 + sw, &vs[(wid*2+1) * 512]);
    __syncthreads();
    // QK^T
    f32x4 sc[4];
#pragma unroll
    for (int j = 0; j < 4; ++j) {
      s16x8 kh0 = *(const s16x8*)&ks[(j*16 + lm) * 64 + pc0];
      s16x8 kh1 = *(const s16x8*)&ks[(j*16 + lm) * 64 + (pc0 ^ 32)];
      f32x4 c = (f32x4)(0.0f);
      c = __builtin_amdgcn_mfma_f32_16x16x32_bf16(qh[0], kh0, c, 0, 0, 0);
      c = __builtin_amdgcn_mfma_f32_16x16x32_bf16(qh[1], kh1, c, 0, 0, 0);
      sc[j] = c;
    }
    // mask + deferred-max base-2 softmax per q-row (reg r)
#pragma unroll
    for (int r = 0; r < 4; ++r) {
      size_t mrow = ((size_t)(b*SLQ + qw + lg*4 + r)) * (SLK/32) + (j0 >> 5);
      u32 w0 = mbits[mrow], w1 = mbits[mrow + 1];
      float sv[4];
#pragma unroll
      for (int j = 0; j < 4; ++j) {
        u32 w = (j < 2) ? w0 : w1;
        int bit = (w >> ((j*16 + lm) & 31)) & 1;
        sv[j] = bit ? sc[j][r] * C2 : -1e9f;
      }
      float pmax = fmaxf(fmaxf(sv[0], sv[1]), fmaxf(sv[2], sv[3]));
      if (!__all(pmax <= m_r[r] + 8.0f)) {       // slow path: rare
        float mx = pmax;
#pragma unroll
        for (int off = 1; off < 16; off <<= 1) mx = fmaxf(mx, __shfl_xor(mx, off, 64));
        float mnew  = fmaxf(m_r[r], mx);
        float alpha = EXP2(m_r[r] - mnew);       // m=-inf -> 0
        m_r[r] = mnew;
        l_r[r] *= alpha;
#pragma unroll
        for (int j = 0; j < 4; ++j) O[j][r] *= alpha;
      }
      float p0 = EXP2(sv[0] - m_r[r]);
      float p1 = EXP2(sv[1] - m_r[r]);
      float p2 = EXP2(sv[2] - m_r[r]);
      float p3 = EXP2(sv[3] - m_r[r]);
      l_r[r] += (p0 + p1) + (p2 + p3);
      u32 pk01 = cvtpk(p0, p1);
      u32 pk23 = cvtpk(p2, p3);
      ps[wid][lg*4 + r][0*16 + lm] = (u16)(pk01 & 0xffffu);
      ps[wid][lg*4 + r][1*16 + lm] = (u16)(pk01 >> 16);
      ps[wid][lg*4 + r][2*16 + lm] = (u16)(pk23 & 0xffffu);
      ps[wid][lg*4 + r][3*16 + lm] = (u16)(pk23 >> 16);
    }
    // PV (vs rows = dv, cols = key; same swizzled read col)
    {
      s16x8 pa0 = *(const s16x8*)&ps[wid][lm][lg*8];
      s16x8 pa1 = *(const s16x8*)&ps[wid][lm][32 + lg*8];
#pragma unroll
      for (int j = 0; j < 4; ++j) {
        s16x8 vb0 = *(const s16x8*)&vs[(j*16 + lm) * 64 + pc0];
        s16x8 vb1 = *(const s16x8*)&vs[(j*16 + lm) * 64 + (pc0 ^ 32)];
        O[j] = __builtin_amdgcn_mfma_f32_16x16x32_bf16(pa0, vb0, O[j], 0, 0, 0);
        O[j] = __builtin_amdgcn_mfma_f32_16x16x32_bf16(pa1, vb1, O[j], 0, 0, 0);
      }
    }
    __syncthreads();
  }
  // final l reduction across the 16 lanes of each row (once)
#pragma unroll
  for (int r = 0; r < 4; ++r) {
#pragma unroll
    for (int off = 1; off < 16; off <<= 1) l_r[r] += __shfl_xor(l_r[r], off, 64);
  }
#pragma unroll
  for (int j = 0; j < 4; ++j)
#pragma unroll
    for (int r = 0; r < 4; ++r) {
      float v = O[j][r] / l_r[r];
      size_t row = (size_t)(b*SLQ + qw + lg*4 + r);
      wv[row*DM + h*HD + j*16 + lm] = f2bf(v);
    }
  if (lm == 0) {
#pragma unroll
    for (int r = 0; r < 4; ++r) {
      float* mp = ml + ((size_t)(b*NH + h)*SLQ + qw + lg*4 + r) * 2;
      mp[0] = m_r[r]; mp[1] = l_r[r];   // m in base-2 units
    }
  }
}

// ---------------------------------------------------------------------------
// tail_k: fused wmean + output projection (one launch, 2304 blocks):
//   [0,256)     gemm_o: out0 = wvb@WoT + bo (f32) -- dispatched first.
//   [256,2304)  wmean: one 64q x 64k tile; LDS-staged K with DOUBLE BUFFER
//               across the h-loop (stage h+1 while computing h; ONE barrier
//               per head). Bitwise-identical accumulation order.
// LDS: 9216 u16 = 18 KB (gemm_o uses 8192 u16; wmean dbuf uses 9216).
// ---------------------------------------------------------------------------
__global__ __launch_bounds__(256) void tail_k(
    const u16* __restrict__ qb, const u16* __restrict__ kb,
    const u32* __restrict__ mbits, const float* __restrict__ ml,
    float* __restrict__ out1,
    const u16* __restrict__ wvb, const u16* __restrict__ WoT,
    const float* __restrict__ bo, float* __restrict__ out0) {
  __shared__ u16 lds[9216];   // 18 KB
  const int gid = blockIdx.x, t = threadIdx.x;
  const int wid = t >> 6, lane = t & 63, lg = lane >> 4, lm = lane & 15;

  if (gid < 256) {
    // ---- output projection ----
    u16* Ah = lds;
    u16* Bh = lds + 128 * 32;
    const int m0 = (gid >> 3) * 128, n0 = (gid & 7) * 128;
    const int wr = wid >> 1, wc = wid & 1;
    f32x4 acc[4][4];
#pragma unroll
    for (int i = 0; i < 4; ++i)
#pragma unroll
      for (int j = 0; j < 4; ++j) acc[i][j] = (f32x4)(0.0f);
    const int c0 = wid * 2, c1 = wid * 2 + 1;
    const int sr0 = c0 * 16 + (lane >> 2), sr1 = c1 * 16 + (lane >> 2);
    const int spc = (lane & 3) * 8;
    for (int k0 = 0; k0 < DM; k0 += 32) {
      gl16(wvb + (size_t)(m0 + sr0) * DM + k0 + spc, &Ah[c0 * 512]);
      gl16(wvb + (size_t)(m0 + sr1) * DM + k0 + spc, &Ah[c1 * 512]);
      gl16(WoT + (size_t)(n0 + sr0) * DM + k0 + spc, &Bh[c0 * 512]);
      gl16(WoT + (size_t)(n0 + sr1) * DM + k0 + spc, &Bh[c1 * 512]);
      __syncthreads();
      s16x8 ah[4], bh[4];
#pragma unroll
      for (int i = 0; i < 4; ++i) {
        ah[i] = *(const s16x8*)&Ah[(wr*64 + i*16 + lm) * 32 + lg*8];
        bh[i] = *(const s16x8*)&Bh[(wc*64 + i*16 + lm) * 32 + lg*8];
      }
#pragma unroll
      for (int i = 0; i < 4; ++i)
#pragma unroll
        for (int j = 0; j < 4; ++j)
          acc[i][j] = __builtin_amdgcn_mfma_f32_16x16x32_bf16(ah[i], bh[j], acc[i][j], 0, 0, 0);
      __syncthreads();
    }
#pragma unroll
    for (int i = 0; i < 4; ++i)
#pragma unroll
      for (int j = 0; j < 4; ++j) {
        const int colg = n0 + wc*64 + j*16 + lm;
        const int rowb = m0 + wr*64 + i*16 + lg*4;
        const float bcol = bo[colg];
#pragma unroll
        for (int r = 0; r < 4; ++r)
          out0[(size_t)(rowb + r) * DM + colg] = acc[i][j][r] + bcol;
      }
  } else {
    // ---- weight_mean tile: double-buffered K staging across heads ----
    u16 (*ks)[72] = (u16(*)[72])lds;   // rows [0,64)=buf0, [64,128)=buf1
    const int g = gid - 256;
    const int j0 = (g & 31) * 64, q0 = ((g >> 5) & 15) * 64, b = g >> 9;
    const int qw = q0 + wid * 16;
    const int srow = t >> 2, sch = t & 3;
    f32x4 wm[4];
#pragma unroll
    for (int j = 0; j < 4; ++j) wm[j] = (f32x4)(0.0f);
    u32 w0[4], w1[4];
#pragma unroll
    for (int r = 0; r < 4; ++r) {
      size_t mrow = ((size_t)(b*SLQ + qw + lg*4 + r)) * (SLK/32) + (j0 >> 5);
      w0[r] = mbits[mrow]; w1[r] = mbits[mrow + 1];
    }
    // stage head 0 into buf0
    {
      size_t koff = ((size_t)(b*SLK + j0 + srow)) * DM + 0*HD + sch*16;
      *(s16x8*)&ks[srow][sch*16]     = *(const s16x8*)(kb + koff);
      *(s16x8*)&ks[srow][sch*16 + 8] = *(const s16x8*)(kb + koff + 8);
    }
    __syncthreads();
    for (int h = 0; h < NH; ++h) {
      const int cur = h & 1;
      if (h + 1 < NH) {   // stage next head into the other buffer
        const int nxt = cur ^ 1;
        size_t koff = ((size_t)(b*SLK + j0 + srow)) * DM + (h+1)*HD + sch*16;
        *(s16x8*)&ks[nxt*64 + srow][sch*16]     = *(const s16x8*)(kb + koff);
        *(s16x8*)&ks[nxt*64 + srow][sch*16 + 8] = *(const s16x8*)(kb + koff + 8);
      }
      s16x8 qh0, qh1;
      {
        size_t off = ((size_t)(b*SLQ + qw + lm)) * DM + h*HD + lg*8;
        qh0 = *(const s16x8*)(qb + off);
        qh1 = *(const s16x8*)(qb + off + 32);
      }
      float mr[4], li[4];
#pragma unroll
      for (int r = 0; r < 4; ++r) {
        const float* mp = ml + ((size_t)(b*NH + h)*SLQ + qw + lg*4 + r) * 2;
        mr[r] = mp[0]; li[r] = 1.0f / mp[1];
      }
#pragma unroll
      for (int j = 0; j < 4; ++j) {
        s16x8 kh0 = *(const s16x8*)&ks[cur*64 + j*16 + lm][lg*8];
        s16x8 kh1 = *(const s16x8*)&ks[cur*64 + j*16 + lm][32 + lg*8];
        f32x4 c = (f32x4)(0.0f);
        c = __builtin_amdgcn_mfma_f32_16x16x32_bf16(qh0, kh0, c, 0, 0, 0);
        c = __builtin_amdgcn_mfma_f32_16x16x32_bf16(qh1, kh1, c, 0, 0, 0);
#pragma unroll
        for (int r = 0; r < 4; ++r) {
          u32 w = (j < 2) ? w0[r] : w1[r];
          int bit = (w >> ((j*16 + lm) & 31)) & 1;
          float wvv = bit ? EXP2(__builtin_fmaf(c[r], C2, -mr[r])) * li[r] : 0.f;
          wm[j][r] += wvv;
        }
      }
      __syncthreads();  // next-head staging complete; cur reads done
    }
#pragma unroll
    for (int j = 0; j < 4; ++j)
#pragma unroll
      for (int r = 0; r < 4; ++r)
        out1[((size_t)b*SLQ + qw + lg*4 + r) * SLK + j0 + j*16 + lm]
            = wm[j][r] * (1.0f / NH);
  }
}

// ---------------------------------------------------------------------------
extern "C" void kernel_launch(void* const* d_in, const int* in_sizes, int n_in,
                              void* d_out, int out_size, void* d_ws, size_t ws_size,
                              hipStream_t stream) {
  const float* mq    = (const float*)d_in[0];
  const float* reply = (const float*)d_in[1];
  const int*   maskp = (const int*)  d_in[2];
  const float* Wq = (const float*)d_in[3];
  const float* bq = (const float*)d_in[4];
  const float* Wk = (const float*)d_in[5];
  const float* bk = (const float*)d_in[6];
  const float* Wv = (const float*)d_in[7];
  const float* bv = (const float*)d_in[8];
  const float* Wo = (const float*)d_in[9];
  const float* bo = (const float*)d_in[10];

  float* out0 = (float*)d_out;
  float* out1 = out0 + (size_t)NB*SLQ*DM;

  // workspace carve -- total ~82 MB
  char* w = (char*)d_ws;
  auto carve = [&](size_t bytes) { char* p = w; w += bytes; return p; };
  u16* WqT = (u16*)carve((size_t)DM*DM*2);
  u16* WkT = (u16*)carve((size_t)DM*DM*2);
  u16* WvT = (u16*)carve((size_t)DM*DM*2);
  u16* WoT = (u16*)carve((size_t)DM*DM*2);
  u16* mqb = (u16*)carve((size_t)NB*SLQ*DM*2);
  u16* rpb = (u16*)carve((size_t)NB*SLK*DM*2);
  u16* qbf = (u16*)carve((size_t)NB*SLQ*DM*2);
  u16* kbf = (u16*)carve((size_t)NB*SLK*DM*2);
  u16* vT  = (u16*)carve((size_t)NB*SLK*DM*2);
  u16* wvb = (u16*)carve((size_t)NB*SLQ*DM*2);
  float* mlb = (float*)carve((size_t)NB*NH*SLQ*2*4);
  unsigned long long* mbits = (unsigned long long*)carve((size_t)NB*SLQ*SLK/8);

  // fused setup: maskbits + cvt(x2) + convT(x4) in one launch
  prep_k<<<2048, 256, 0, stream>>>(
      maskp, mbits, mq, mqb, reply, rpb,
      Wq, Wk, Wv, Wo, WqT, WkT, WvT, WoT);

  // grouped q/k/v projections
  proj_gemm_k<<<1280, 256, 0, stream>>>(
      mqb, rpb, WqT, WkT, WvT, bq, bk, bv, qbf, kbf, vT);

  attn_mfma_k<<<dim3(SLQ/64, NH, NB), 256, 0, stream>>>(
      qbf, kbf, vT, (const u32*)mbits, wvb, mlb);

  // fused tail: output projection (256 blocks, first) + weight_mean (2048)
  tail_k<<<2304, 256, 0, stream>>>(
      qbf, kbf, (const u32*)mbits, mlb, out1, wvb, WoT, bo, out0);
}

// Round 17
// 272.499 us; speedup vs baseline: 1.1351x; 1.1351x over previous
//
#include <hip/hip_runtime.h>
#include <math.h>

#define NB   4
#define NH   16
#define SLQ  1024
#define SLK  2048
#define DM   1024
#define HD   64

typedef __attribute__((ext_vector_type(8))) short s16x8;
typedef __attribute__((ext_vector_type(4))) short s16x4;
typedef __attribute__((ext_vector_type(4))) float f32x4;
typedef unsigned short u16;
typedef unsigned int   u32;

#if defined(__has_builtin)
#if __has_builtin(__builtin_amdgcn_exp2f)
#define EXP2(x) __builtin_amdgcn_exp2f(x)
#else
#define EXP2(x) exp2f(x)
#endif
#else
#define EXP2(x) exp2f(x)
#endif

// 0.125 * log2(e): scores scaled to base-2 inside attn/wmean
#define C2 0.18033688011116012f

__device__ inline u16 f2bf(float f) {
  u32 u = __float_as_uint(f);
  u32 r = u + 0x7fffu + ((u >> 16) & 1u);
  return (u16)(r >> 16);
}
__device__ inline float bf2f(u16 h) { return __uint_as_float(((u32)h) << 16); }

// pack 2 f32 -> 2 bf16 (RNE), lo = a, hi = b
__device__ __forceinline__ u32 cvtpk(float a, float b) {
  u32 r;
  asm("v_cvt_pk_bf16_f32 %0, %1, %2" : "=v"(r) : "v"(a), "v"(b));
  return r;
}

// async global->LDS, 16B per lane; LDS dest must be wave-uniform base.
__device__ __forceinline__ void gl16(const void* g, void* l) {
  __builtin_amdgcn_global_load_lds(
      (const __attribute__((address_space(1))) unsigned int*)g,
      (__attribute__((address_space(3))) unsigned int*)l, 16, 0, 0);
}

// shared convT tile body: W[64x64 tile] f32 -> T[n][k] bf16 (transposed)
__device__ __forceinline__ void convT_tile(
    const float* __restrict__ W, u16* __restrict__ T,
    float (*ts)[68], int cx, int ry, int t) {
  const int r0 = ry * 64, c0 = cx * 64;
  const int rr = t >> 4, cc = t & 15;
#pragma unroll
  for (int p = 0; p < 4; ++p) {
    float4 v = *(const float4*)(W + (size_t)(r0 + rr + p*16) * DM + c0 + cc*4);
    *(float4*)&ts[rr + p*16][cc*4] = v;
  }
  __syncthreads();
  const int c = t >> 2, ch = t & 3;
  s16x8 h0, h1;
#pragma unroll
  for (int i = 0; i < 8; ++i) {
    h0[i] = (short)f2bf(ts[ch*16 + i][c]);
    h1[i] = (short)f2bf(ts[ch*16 + 8 + i][c]);
  }
  size_t base = (size_t)(c0 + c) * DM + r0 + ch*16;
  *(s16x8*)(T + base) = h0; *(s16x8*)(T + base + 8) = h1;
}

// ---------------------------------------------------------------------------
// prep_k: setup needed BEFORE proj: 1536 blocks by range:
//   [0,768)    f32 -> bf16 for mq and reply (grid-stride)
//   [768,1536) 3x W{q,k,v} -> WT bf16 (tile per block)
// (maskbits + Wo convT moved into the proj launch -- not proj dependencies.)
// ---------------------------------------------------------------------------
__global__ __launch_bounds__(256) void prep_k(
    const float* __restrict__ mq, u16* __restrict__ mqb,
    const float* __restrict__ reply, u16* __restrict__ rpb,
    const float* __restrict__ W0, const float* __restrict__ W1,
    const float* __restrict__ W2,
    u16* __restrict__ T0, u16* __restrict__ T1, u16* __restrict__ T2) {
  __shared__ float ts[64][68];
  const int gid = blockIdx.x, t = threadIdx.x;
  if (gid < 768) {
    const int na = NB*SLQ*DM, nb = NB*SLK*DM;
    const int stride = 768 * 256 * 8;
    for (int i = (gid * 256 + t) * 8; i < na + nb; i += stride) {
      const float* s; u16* d; int off;
      if (i < na) { s = mq; d = mqb; off = i; } else { s = reply; d = rpb; off = i - na; }
      float4 x = *(const float4*)(s + off);
      float4 y = *(const float4*)(s + off + 4);
      s16x8 o;
      o[0] = (short)f2bf(x.x); o[1] = (short)f2bf(x.y);
      o[2] = (short)f2bf(x.z); o[3] = (short)f2bf(x.w);
      o[4] = (short)f2bf(y.x); o[5] = (short)f2bf(y.y);
      o[6] = (short)f2bf(y.z); o[7] = (short)f2bf(y.w);
      *(s16x8*)(d + off) = o;
    }
  } else {
    const int g = gid - 768;
    const int cx = g & 15, ry = (g >> 4) & 15, wz = g >> 8;   // wz 0..2
    const float* W = (wz == 0) ? W0 : (wz == 1) ? W1 : W2;
    u16* T        = (wz == 0) ? T0 : (wz == 1) ? T1 : T2;
    convT_tile(W, T, ts, cx, ry, t);
  }
}

// ---------------------------------------------------------------------------
// proj_gemm_k: 1792 blocks by range:
//   [0,256)    maskbits (grid-stride ballot)            -- memory, early
//   [256,512)  convT of Wo -> WoT                        -- memory, early
//   [512,768)  q-proj (natural bf16)
//   [768,1792) k/v proj, INTERLEAVED pairs sharing A-tiles (k natural,
//              v transposed vT)
// The 512 memory blocks hide under ~80us of GEMM compute.
// ---------------------------------------------------------------------------
__global__ __launch_bounds__(256) void proj_gemm_k(
    const int* __restrict__ mask, unsigned long long* __restrict__ bits,
    const float* __restrict__ Wo, u16* __restrict__ WoT,
    const u16* __restrict__ mqb, const u16* __restrict__ rpb,
    const u16* __restrict__ WqT, const u16* __restrict__ WkT,
    const u16* __restrict__ WvT,
    const float* __restrict__ bq, const float* __restrict__ bk,
    const float* __restrict__ bv,
    u16* __restrict__ qbf, u16* __restrict__ kbf, u16* __restrict__ vTp) {
  __shared__ char ldsraw[64 * 68 * 4];   // 17408 B, shared by all branches
  const int gid = blockIdx.x, t = threadIdx.x;

  if (gid < 256) {
    // ---- maskbits ----
    const int nwords = NB*SLQ*SLK/64;
    int gw   = (gid * 256 + t) >> 6;
    int lane = t & 63;
    const int nw = (256 * 256) >> 6;   // 1024 waves
    for (int w = gw; w < nwords; w += nw) {
      int m = mask[(size_t)w * 64 + lane];
      unsigned long long b = __ballot(m != 0);
      if (lane == 0) bits[w] = b;
    }
    return;
  }
  if (gid < 512) {
    // ---- convT of Wo ----
    const int g = gid - 256;
    convT_tile(Wo, WoT, (float(*)[68])ldsraw, g & 15, g >> 4, t);
    return;
  }

  // ---- GEMM branches ----
  const u16* A; const u16* BT; const float* bias; u16* out;
  int mode, mt, nt;
  if (gid < 768) {
    const int g = gid - 512;
    A = mqb; BT = WqT; bias = bq; out = qbf; mode = 0;
    nt = g & 7; mt = g >> 3;
  } else {
    const int g = gid - 768, pair = g >> 1;
    nt = pair & 7; mt = pair >> 3;
    if ((g & 1) == 0) { A = rpb; BT = WkT; bias = bk; out = kbf; mode = 0; }
    else              { A = rpb; BT = WvT; bias = bv; out = vTp; mode = 1; }
  }
  const int m0 = mt * 128, n0 = nt * 128;
  u16* Ah = (u16*)ldsraw;
  u16* Bh = (u16*)(ldsraw + 8192);
  const int wid = t >> 6, lane = t & 63, lg = lane >> 4, lm = lane & 15;
  const int wr = wid >> 1, wc = wid & 1;
  f32x4 acc[4][4];
#pragma unroll
  for (int i = 0; i < 4; ++i)
#pragma unroll
    for (int j = 0; j < 4; ++j) acc[i][j] = (f32x4)(0.0f);

  const int c0 = wid * 2, c1 = wid * 2 + 1;
  const int sr0 = c0 * 16 + (lane >> 2), sr1 = c1 * 16 + (lane >> 2);
  const int spc = (lane & 3) * 8;
  for (int k0 = 0; k0 < DM; k0 += 32) {
    gl16(A  + (size_t)(m0 + sr0) * DM + k0 + spc, &Ah[c0 * 512]);
    gl16(A  + (size_t)(m0 + sr1) * DM + k0 + spc, &Ah[c1 * 512]);
    gl16(BT + (size_t)(n0 + sr0) * DM + k0 + spc, &Bh[c0 * 512]);
    gl16(BT + (size_t)(n0 + sr1) * DM + k0 + spc, &Bh[c1 * 512]);
    __syncthreads();
    s16x8 ah[4], bh[4];
#pragma unroll
    for (int i = 0; i < 4; ++i) {
      ah[i] = *(const s16x8*)&Ah[(wr*64 + i*16 + lm) * 32 + lg*8];
      bh[i] = *(const s16x8*)&Bh[(wc*64 + i*16 + lm) * 32 + lg*8];
    }
#pragma unroll
    for (int i = 0; i < 4; ++i)
#pragma unroll
      for (int j = 0; j < 4; ++j)
        acc[i][j] = __builtin_amdgcn_mfma_f32_16x16x32_bf16(ah[i], bh[j], acc[i][j], 0, 0, 0);
    __syncthreads();
  }
#pragma unroll
  for (int i = 0; i < 4; ++i)
#pragma unroll
    for (int j = 0; j < 4; ++j) {
      const int colg = n0 + wc*64 + j*16 + lm;
      const int rowb = m0 + wr*64 + i*16 + lg*4;
      const float bcol = bias[colg];
      if (mode == 0) {
#pragma unroll
        for (int r = 0; r < 4; ++r)
          out[(size_t)(rowb + r) * DM + colg] = f2bf(acc[i][j][r] + bcol);
      } else {  // vT transposed bf16
        const int bb = rowb >> 11, key = rowb & 2047;
        const int hh = colg >> 6, dv = colg & 63;
        s16x4 pk;
#pragma unroll
        for (int r = 0; r < 4; ++r) pk[r] = (short)f2bf(acc[i][j][r] + bcol);
        *(s16x4*)(out + (((size_t)bb*NH + hh)*HD + dv)*SLK + key) = pk;
      }
    }
}

// ---------------------------------------------------------------------------
// Flash attention (FROZEN round-11 build: 101us, VGPR 64). Base-2 softmax,
// deferred-max, cvt_pk P-store, per-lane l partials. DO NOT MODIFY:
// any VGPR increase past 64 drops occupancy 35->24% and costs ~20us
// (measured rounds 8, 9, 13, 16).
// ---------------------------------------------------------------------------
__global__ __launch_bounds__(256) void attn_mfma_k(
    const u16* __restrict__ qb, const u16* __restrict__ kb,
    const u16* __restrict__ vT, const u32* __restrict__ mbits,
    u16* __restrict__ wv, float* __restrict__ ml) {
  __shared__ u16 ks[64][72];
  __shared__ u16 vs[64][72];
  __shared__ u16 ps[4][16][72];
  const int qt = blockIdx.x, h = blockIdx.y, b = blockIdx.z;
  const int t = threadIdx.x, wid = t >> 6, lane = t & 63, lg = lane >> 4, lm = lane & 15;
  const int q0 = qt * 64, qw = q0 + wid * 16;
  s16x8 qh[2];
#pragma unroll
  for (int s = 0; s < 2; ++s) {
    size_t off = ((size_t)(b*SLQ + qw + lm)) * DM + h*HD + s*32 + lg*8;
    qh[s] = *(const s16x8*)(qb + off);
  }
  f32x4 O[4];
#pragma unroll
  for (int j = 0; j < 4; ++j) O[j] = (f32x4)(0.0f);
  float m_r[4] = {-INFINITY, -INFINITY, -INFINITY, -INFINITY};
  float l_r[4] = {0.f, 0.f, 0.f, 0.f};   // per-lane partials (16 lanes/row)
  const int srow = t >> 2, sch = t & 3;
  for (int j0 = 0; j0 < SLK; j0 += 64) {
    {
      size_t koff = ((size_t)(b*SLK + j0 + srow)) * DM + h*HD + sch*16;
      *(s16x8*)&ks[srow][sch*16]     = *(const s16x8*)(kb + koff);
      *(s16x8*)&ks[srow][sch*16 + 8] = *(const s16x8*)(kb + koff + 8);
      size_t voff = (((size_t)b*NH + h)*HD + srow)*SLK + j0 + sch*16;
      *(s16x8*)&vs[srow][sch*16]     = *(const s16x8*)(vT + voff);
      *(s16x8*)&vs[srow][sch*16 + 8] = *(const s16x8*)(vT + voff + 8);
    }
    __syncthreads();
    // QK^T
    f32x4 sc[4];
#pragma unroll
    for (int j = 0; j < 4; ++j) {
      s16x8 kh0 = *(const s16x8*)&ks[j*16 + lm][lg*8];
      s16x8 kh1 = *(const s16x8*)&ks[j*16 + lm][32 + lg*8];
      f32x4 c = (f32x4)(0.0f);
      c = __builtin_amdgcn_mfma_f32_16x16x32_bf16(qh[0], kh0, c, 0, 0, 0);
      c = __builtin_amdgcn_mfma_f32_16x16x32_bf16(qh[1], kh1, c, 0, 0, 0);
      sc[j] = c;
    }
    // mask + deferred-max base-2 softmax per q-row (reg r)
#pragma unroll
    for (int r = 0; r < 4; ++r) {
      size_t mrow = ((size_t)(b*SLQ + qw + lg*4 + r)) * (SLK/32) + (j0 >> 5);
      u32 w0 = mbits[mrow], w1 = mbits[mrow + 1];
      float sv[4];
#pragma unroll
      for (int j = 0; j < 4; ++j) {
        u32 w = (j < 2) ? w0 : w1;
        int bit = (w >> ((j*16 + lm) & 31)) & 1;
        sv[j] = bit ? sc[j][r] * C2 : -1e9f;
      }
      float pmax = fmaxf(fmaxf(sv[0], sv[1]), fmaxf(sv[2], sv[3]));
      if (!__all(pmax <= m_r[r] + 8.0f)) {       // slow path: rare
        float mx = pmax;
#pragma unroll
        for (int off = 1; off < 16; off <<= 1) mx = fmaxf(mx, __shfl_xor(mx, off, 64));
        float mnew  = fmaxf(m_r[r], mx);
        float alpha = EXP2(m_r[r] - mnew);       // m=-inf -> 0
        m_r[r] = mnew;
        l_r[r] *= alpha;
#pragma unroll
        for (int j = 0; j < 4; ++j) O[j][r] *= alpha;
      }
      float p0 = EXP2(sv[0] - m_r[r]);
      float p1 = EXP2(sv[1] - m_r[r]);
      float p2 = EXP2(sv[2] - m_r[r]);
      float p3 = EXP2(sv[3] - m_r[r]);
      l_r[r] += (p0 + p1) + (p2 + p3);
      u32 pk01 = cvtpk(p0, p1);
      u32 pk23 = cvtpk(p2, p3);
      ps[wid][lg*4 + r][0*16 + lm] = (u16)(pk01 & 0xffffu);
      ps[wid][lg*4 + r][1*16 + lm] = (u16)(pk01 >> 16);
      ps[wid][lg*4 + r][2*16 + lm] = (u16)(pk23 & 0xffffu);
      ps[wid][lg*4 + r][3*16 + lm] = (u16)(pk23 >> 16);
    }
    // PV
    {
      s16x8 pa0 = *(const s16x8*)&ps[wid][lm][lg*8];
      s16x8 pa1 = *(const s16x8*)&ps[wid][lm][32 + lg*8];
#pragma unroll
      for (int j = 0; j < 4; ++j) {
        s16x8 vb0 = *(const s16x8*)&vs[j*16 + lm][lg*8];
        s16x8 vb1 = *(const s16x8*)&vs[j*16 + lm][32 + lg*8];
        O[j] = __builtin_amdgcn_mfma_f32_16x16x32_bf16(pa0, vb0, O[j], 0, 0, 0);
        O[j] = __builtin_amdgcn_mfma_f32_16x16x32_bf16(pa1, vb1, O[j], 0, 0, 0);
      }
    }
    __syncthreads();
  }
  // final l reduction across the 16 lanes of each row (once)
#pragma unroll
  for (int r = 0; r < 4; ++r) {
#pragma unroll
    for (int off = 1; off < 16; off <<= 1) l_r[r] += __shfl_xor(l_r[r], off, 64);
  }
#pragma unroll
  for (int j = 0; j < 4; ++j)
#pragma unroll
    for (int r = 0; r < 4; ++r) {
      float v = O[j][r] / l_r[r];
      size_t row = (size_t)(b*SLQ + qw + lg*4 + r);
      wv[row*DM + h*HD + j*16 + lm] = f2bf(v);
    }
  if (lm == 0) {
#pragma unroll
    for (int r = 0; r < 4; ++r) {
      float* mp = ml + ((size_t)(b*NH + h)*SLQ + qw + lg*4 + r) * 2;
      mp[0] = m_r[r]; mp[1] = l_r[r];   // m in base-2 units
    }
  }
}

// ---------------------------------------------------------------------------
// tail_k: fused wmean + output projection (one launch, 2304 blocks):
//   [0,256)     gemm_o: out0 = wvb@WoT + bo (f32) -- dispatched first.
//   [256,2304)  wmean: one 64q x 64k tile; LDS-staged K with DOUBLE BUFFER
//               across the h-loop (stage h+1 while computing h; ONE barrier
//               per head). Bitwise-identical accumulation order.
// LDS: 9216 u16 = 18 KB (gemm_o uses 8192 u16; wmean dbuf uses 9216).
// ---------------------------------------------------------------------------
__global__ __launch_bounds__(256) void tail_k(
    const u16* __restrict__ qb, const u16* __restrict__ kb,
    const u32* __restrict__ mbits, const float* __restrict__ ml,
    float* __restrict__ out1,
    const u16* __restrict__ wvb, const u16* __restrict__ WoT,
    const float* __restrict__ bo, float* __restrict__ out0) {
  __shared__ u16 lds[9216];   // 18 KB
  const int gid = blockIdx.x, t = threadIdx.x;
  const int wid = t >> 6, lane = t & 63, lg = lane >> 4, lm = lane & 15;

  if (gid < 256) {
    // ---- output projection ----
    u16* Ah = lds;
    u16* Bh = lds + 128 * 32;
    const int m0 = (gid >> 3) * 128, n0 = (gid & 7) * 128;
    const int wr = wid >> 1, wc = wid & 1;
    f32x4 acc[4][4];
#pragma unroll
    for (int i = 0; i < 4; ++i)
#pragma unroll
      for (int j = 0; j < 4; ++j) acc[i][j] = (f32x4)(0.0f);
    const int c0 = wid * 2, c1 = wid * 2 + 1;
    const int sr0 = c0 * 16 + (lane >> 2), sr1 = c1 * 16 + (lane >> 2);
    const int spc = (lane & 3) * 8;
    for (int k0 = 0; k0 < DM; k0 += 32) {
      gl16(wvb + (size_t)(m0 + sr0) * DM + k0 + spc, &Ah[c0 * 512]);
      gl16(wvb + (size_t)(m0 + sr1) * DM + k0 + spc, &Ah[c1 * 512]);
      gl16(WoT + (size_t)(n0 + sr0) * DM + k0 + spc, &Bh[c0 * 512]);
      gl16(WoT + (size_t)(n0 + sr1) * DM + k0 + spc, &Bh[c1 * 512]);
      __syncthreads();
      s16x8 ah[4], bh[4];
#pragma unroll
      for (int i = 0; i < 4; ++i) {
        ah[i] = *(const s16x8*)&Ah[(wr*64 + i*16 + lm) * 32 + lg*8];
        bh[i] = *(const s16x8*)&Bh[(wc*64 + i*16 + lm) * 32 + lg*8];
      }
#pragma unroll
      for (int i = 0; i < 4; ++i)
#pragma unroll
        for (int j = 0; j < 4; ++j)
          acc[i][j] = __builtin_amdgcn_mfma_f32_16x16x32_bf16(ah[i], bh[j], acc[i][j], 0, 0, 0);
      __syncthreads();
    }
#pragma unroll
    for (int i = 0; i < 4; ++i)
#pragma unroll
      for (int j = 0; j < 4; ++j) {
        const int colg = n0 + wc*64 + j*16 + lm;
        const int rowb = m0 + wr*64 + i*16 + lg*4;
        const float bcol = bo[colg];
#pragma unroll
        for (int r = 0; r < 4; ++r)
          out0[(size_t)(rowb + r) * DM + colg] = acc[i][j][r] + bcol;
      }
  } else {
    // ---- weight_mean tile: double-buffered K staging across heads ----
    u16 (*ks)[72] = (u16(*)[72])lds;   // rows [0,64)=buf0, [64,128)=buf1
    const int g = gid - 256;
    const int j0 = (g & 31) * 64, q0 = ((g >> 5) & 15) * 64, b = g >> 9;
    const int qw = q0 + wid * 16;
    const int srow = t >> 2, sch = t & 3;
    f32x4 wm[4];
#pragma unroll
    for (int j = 0; j < 4; ++j) wm[j] = (f32x4)(0.0f);
    u32 w0[4], w1[4];
#pragma unroll
    for (int r = 0; r < 4; ++r) {
      size_t mrow = ((size_t)(b*SLQ + qw + lg*4 + r)) * (SLK/32) + (j0 >> 5);
      w0[r] = mbits[mrow]; w1[r] = mbits[mrow + 1];
    }
    // stage head 0 into buf0
    {
      size_t koff = ((size_t)(b*SLK + j0 + srow)) * DM + 0*HD + sch*16;
      *(s16x8*)&ks[srow][sch*16]     = *(const s16x8*)(kb + koff);
      *(s16x8*)&ks[srow][sch*16 + 8] = *(const s16x8*)(kb + koff + 8);
    }
    __syncthreads();
    for (int h = 0; h < NH; ++h) {
      const int cur = h & 1;
      if (h + 1 < NH) {   // stage next head into the other buffer
        const int nxt = cur ^ 1;
        size_t koff = ((size_t)(b*SLK + j0 + srow)) * DM + (h+1)*HD + sch*16;
        *(s16x8*)&ks[nxt*64 + srow][sch*16]     = *(const s16x8*)(kb + koff);
        *(s16x8*)&ks[nxt*64 + srow][sch*16 + 8] = *(const s16x8*)(kb + koff + 8);
      }
      s16x8 qh0, qh1;
      {
        size_t off = ((size_t)(b*SLQ + qw + lm)) * DM + h*HD + lg*8;
        qh0 = *(const s16x8*)(qb + off);
        qh1 = *(const s16x8*)(qb + off + 32);
      }
      float mr[4], li[4];
#pragma unroll
      for (int r = 0; r < 4; ++r) {
        const float* mp = ml + ((size_t)(b*NH + h)*SLQ + qw + lg*4 + r) * 2;
        mr[r] = mp[0]; li[r] = 1.0f / mp[1];
      }
#pragma unroll
      for (int j = 0; j < 4; ++j) {
        s16x8 kh0 = *(const s16x8*)&ks[cur*64 + j*16 + lm][lg*8];
        s16x8 kh1 = *(const s16x8*)&ks[cur*64 + j*16 + lm][32 + lg*8];
        f32x4 c = (f32x4)(0.0f);
        c = __builtin_amdgcn_mfma_f32_16x16x32_bf16(qh0, kh0, c, 0, 0, 0);
        c = __builtin_amdgcn_mfma_f32_16x16x32_bf16(qh1, kh1, c, 0, 0, 0);
#pragma unroll
        for (int r = 0; r < 4; ++r) {
          u32 w = (j < 2) ? w0[r] : w1[r];
          int bit = (w >> ((j*16 + lm) & 31)) & 1;
          float wvv = bit ? EXP2(__builtin_fmaf(c[r], C2, -mr[r])) * li[r] : 0.f;
          wm[j][r] += wvv;
        }
      }
      __syncthreads();  // next-head staging complete; cur reads done
    }
#pragma unroll
    for (int j = 0; j < 4; ++j)
#pragma unroll
      for (int r = 0; r < 4; ++r)
        out1[((size_t)b*SLQ + qw + lg*4 + r) * SLK + j0 + j*16 + lm]
            = wm[j][r] * (1.0f / NH);
  }
}

// ---------------------------------------------------------------------------
extern "C" void kernel_launch(void* const* d_in, const int* in_sizes, int n_in,
                              void* d_out, int out_size, void* d_ws, size_t ws_size,
                              hipStream_t stream) {
  const float* mq    = (const float*)d_in[0];
  const float* reply = (const float*)d_in[1];
  const int*   maskp = (const int*)  d_in[2];
  const float* Wq = (const float*)d_in[3];
  const float* bq = (const float*)d_in[4];
  const float* Wk = (const float*)d_in[5];
  const float* bk = (const float*)d_in[6];
  const float* Wv = (const float*)d_in[7];
  const float* bv = (const float*)d_in[8];
  const float* Wo = (const float*)d_in[9];
  const float* bo = (const float*)d_in[10];

  float* out0 = (float*)d_out;
  float* out1 = out0 + (size_t)NB*SLQ*DM;

  // workspace carve -- total ~82 MB
  char* w = (char*)d_ws;
  auto carve = [&](size_t bytes) { char* p = w; w += bytes; return p; };
  u16* WqT = (u16*)carve((size_t)DM*DM*2);
  u16* WkT = (u16*)carve((size_t)DM*DM*2);
  u16* WvT = (u16*)carve((size_t)DM*DM*2);
  u16* WoT = (u16*)carve((size_t)DM*DM*2);
  u16* mqb = (u16*)carve((size_t)NB*SLQ*DM*2);
  u16* rpb = (u16*)carve((size_t)NB*SLK*DM*2);
  u16* qbf = (u16*)carve((size_t)NB*SLQ*DM*2);
  u16* kbf = (u16*)carve((size_t)NB*SLK*DM*2);
  u16* vT  = (u16*)carve((size_t)NB*SLK*DM*2);
  u16* wvb = (u16*)carve((size_t)NB*SLQ*DM*2);
  float* mlb = (float*)carve((size_t)NB*NH*SLQ*2*4);
  unsigned long long* mbits = (unsigned long long*)carve((size_t)NB*SLQ*SLK/8);

  // setup needed before proj: cvt(x2) + convT(Wq,Wk,Wv)
  prep_k<<<1536, 256, 0, stream>>>(
      mq, mqb, reply, rpb, Wq, Wk, Wv, WqT, WkT, WvT);

  // proj launch: maskbits + convT(Wo) (memory, hide under GEMMs) + q/k/v proj
  proj_gemm_k<<<1792, 256, 0, stream>>>(
      maskp, mbits, Wo, WoT,
      mqb, rpb, WqT, WkT, WvT, bq, bk, bv, qbf, kbf, vT);

  attn_mfma_k<<<dim3(SLQ/64, NH, NB), 256, 0, stream>>>(
      qbf, kbf, vT, (const u32*)mbits, wvb, mlb);

  // fused tail: output projection (256 blocks, first) + weight_mean (2048)
  tail_k<<<2304, 256, 0, stream>>>(
      qbf, kbf, (const u32*)mbits, mlb, out1, wvb, WoT, bo, out0);
}

// Round 18
// 249.700 us; speedup vs baseline: 1.2387x; 1.0913x over previous
//
#include <hip/hip_runtime.h>
#include <math.h>

#define NB   4
#define NH   16
#define SLQ  1024
#define SLK  2048
#define DM   1024
#define HD   64

typedef __attribute__((ext_vector_type(8))) short s16x8;
typedef __attribute__((ext_vector_type(4))) short s16x4;
typedef __attribute__((ext_vector_type(4))) float f32x4;
typedef unsigned short u16;
typedef unsigned int   u32;

#if defined(__has_builtin)
#if __has_builtin(__builtin_amdgcn_exp2f)
#define EXP2(x) __builtin_amdgcn_exp2f(x)
#else
#define EXP2(x) exp2f(x)
#endif
#else
#define EXP2(x) exp2f(x)
#endif

// 0.125 * log2(e): scores scaled to base-2 inside attn/wmean
#define C2 0.18033688011116012f

__device__ inline u16 f2bf(float f) {
  u32 u = __float_as_uint(f);
  u32 r = u + 0x7fffu + ((u >> 16) & 1u);
  return (u16)(r >> 16);
}
__device__ inline float bf2f(u16 h) { return __uint_as_float(((u32)h) << 16); }

// pack 2 f32 -> 2 bf16 (RNE), lo = a, hi = b
__device__ __forceinline__ u32 cvtpk(float a, float b) {
  u32 r;
  asm("v_cvt_pk_bf16_f32 %0, %1, %2" : "=v"(r) : "v"(a), "v"(b));
  return r;
}

// async global->LDS, 16B per lane; LDS dest must be wave-uniform base.
__device__ __forceinline__ void gl16(const void* g, void* l) {
  __builtin_amdgcn_global_load_lds(
      (const __attribute__((address_space(1))) unsigned int*)g,
      (__attribute__((address_space(3))) unsigned int*)l, 16, 0, 0);
}

// shared convT tile body: W[64x64 tile] f32 -> T[n][k] bf16 (transposed)
__device__ __forceinline__ void convT_tile(
    const float* __restrict__ W, u16* __restrict__ T,
    float (*ts)[68], int cx, int ry, int t) {
  const int r0 = ry * 64, c0 = cx * 64;
  const int rr = t >> 4, cc = t & 15;
#pragma unroll
  for (int p = 0; p < 4; ++p) {
    float4 v = *(const float4*)(W + (size_t)(r0 + rr + p*16) * DM + c0 + cc*4);
    *(float4*)&ts[rr + p*16][cc*4] = v;
  }
  __syncthreads();
  const int c = t >> 2, ch = t & 3;
  s16x8 h0, h1;
#pragma unroll
  for (int i = 0; i < 8; ++i) {
    h0[i] = (short)f2bf(ts[ch*16 + i][c]);
    h1[i] = (short)f2bf(ts[ch*16 + 8 + i][c]);
  }
  size_t base = (size_t)(c0 + c) * DM + r0 + ch*16;
  *(s16x8*)(T + base) = h0; *(s16x8*)(T + base + 8) = h1;
}

// ---------------------------------------------------------------------------
// prep_k: setup needed BEFORE proj: 1536 blocks by range:
//   [0,768)    f32 -> bf16 for mq and reply (grid-stride)
//   [768,1536) 3x W{q,k,v} -> WT bf16 (tile per block)
// ---------------------------------------------------------------------------
__global__ __launch_bounds__(256) void prep_k(
    const float* __restrict__ mq, u16* __restrict__ mqb,
    const float* __restrict__ reply, u16* __restrict__ rpb,
    const float* __restrict__ W0, const float* __restrict__ W1,
    const float* __restrict__ W2,
    u16* __restrict__ T0, u16* __restrict__ T1, u16* __restrict__ T2) {
  __shared__ float ts[64][68];
  const int gid = blockIdx.x, t = threadIdx.x;
  if (gid < 768) {
    const int na = NB*SLQ*DM, nb = NB*SLK*DM;
    const int stride = 768 * 256 * 8;
    for (int i = (gid * 256 + t) * 8; i < na + nb; i += stride) {
      const float* s; u16* d; int off;
      if (i < na) { s = mq; d = mqb; off = i; } else { s = reply; d = rpb; off = i - na; }
      float4 x = *(const float4*)(s + off);
      float4 y = *(const float4*)(s + off + 4);
      s16x8 o;
      o[0] = (short)f2bf(x.x); o[1] = (short)f2bf(x.y);
      o[2] = (short)f2bf(x.z); o[3] = (short)f2bf(x.w);
      o[4] = (short)f2bf(y.x); o[5] = (short)f2bf(y.y);
      o[6] = (short)f2bf(y.z); o[7] = (short)f2bf(y.w);
      *(s16x8*)(d + off) = o;
    }
  } else {
    const int g = gid - 768;
    const int cx = g & 15, ry = (g >> 4) & 15, wz = g >> 8;   // wz 0..2
    const float* W = (wz == 0) ? W0 : (wz == 1) ? W1 : W2;
    u16* T        = (wz == 0) ? T0 : (wz == 1) ? T1 : T2;
    convT_tile(W, T, ts, cx, ry, t);
  }
}

// ---------------------------------------------------------------------------
// proj_gemm_k: 1792 blocks by range:
//   [0,256)    maskbits (grid-stride ballot)            -- memory, early
//   [256,512)  convT of Wo -> WoT                        -- memory, early
//   [512,768)  q-proj (natural bf16)
//   [768,1792) k/v proj, INTERLEAVED pairs sharing A-tiles (k natural,
//              v transposed vT)
// GEMM branch: T3-minimum 2-phase pipeline -- double-buffered LDS, issue
// STAGE(next tile) BEFORE current frag-reads+MFMA, ONE barrier per K-step
// (the compiler's vmcnt(0) drain before s_barrier then lands after the
// MFMAs, hiding the staging latency under compute).
// ---------------------------------------------------------------------------
__global__ __launch_bounds__(256) void proj_gemm_k(
    const int* __restrict__ mask, unsigned long long* __restrict__ bits,
    const float* __restrict__ Wo, u16* __restrict__ WoT,
    const u16* __restrict__ mqb, const u16* __restrict__ rpb,
    const u16* __restrict__ WqT, const u16* __restrict__ WkT,
    const u16* __restrict__ WvT,
    const float* __restrict__ bq, const float* __restrict__ bk,
    const float* __restrict__ bv,
    u16* __restrict__ qbf, u16* __restrict__ kbf, u16* __restrict__ vTp) {
  __shared__ char ldsraw[32768];   // 32 KB: 2x(Ah+Bh) dbuf; convT uses 17.4 KB
  const int gid = blockIdx.x, t = threadIdx.x;

  if (gid < 256) {
    // ---- maskbits ----
    const int nwords = NB*SLQ*SLK/64;
    int gw   = (gid * 256 + t) >> 6;
    int lane = t & 63;
    const int nw = (256 * 256) >> 6;   // 1024 waves
    for (int w = gw; w < nwords; w += nw) {
      int m = mask[(size_t)w * 64 + lane];
      unsigned long long b = __ballot(m != 0);
      if (lane == 0) bits[w] = b;
    }
    return;
  }
  if (gid < 512) {
    // ---- convT of Wo ----
    const int g = gid - 256;
    convT_tile(Wo, WoT, (float(*)[68])ldsraw, g & 15, g >> 4, t);
    return;
  }

  // ---- GEMM branches ----
  const u16* A; const u16* BT; const float* bias; u16* out;
  int mode, mt, nt;
  if (gid < 768) {
    const int g = gid - 512;
    A = mqb; BT = WqT; bias = bq; out = qbf; mode = 0;
    nt = g & 7; mt = g >> 3;
  } else {
    const int g = gid - 768, pair = g >> 1;
    nt = pair & 7; mt = pair >> 3;
    if ((g & 1) == 0) { A = rpb; BT = WkT; bias = bk; out = kbf; mode = 0; }
    else              { A = rpb; BT = WvT; bias = bv; out = vTp; mode = 1; }
  }
  const int m0 = mt * 128, n0 = nt * 128;
  // dbuf layout: Ah[bi] at bi*4096, Bh[bi] at 8192 + bi*4096 (u16 units)
  u16* lds16 = (u16*)ldsraw;
  const int wid = t >> 6, lane = t & 63, lg = lane >> 4, lm = lane & 15;
  const int wr = wid >> 1, wc = wid & 1;
  f32x4 acc[4][4];
#pragma unroll
  for (int i = 0; i < 4; ++i)
#pragma unroll
    for (int j = 0; j < 4; ++j) acc[i][j] = (f32x4)(0.0f);

  const int c0 = wid * 2, c1 = wid * 2 + 1;
  const int sr0 = c0 * 16 + (lane >> 2), sr1 = c1 * 16 + (lane >> 2);
  const int spc = (lane & 3) * 8;

#define STAGE(bi, k0)                                                        \
  do {                                                                       \
    gl16(A  + (size_t)(m0 + sr0) * DM + (k0) + spc, &lds16[(bi)*4096 + c0*512]); \
    gl16(A  + (size_t)(m0 + sr1) * DM + (k0) + spc, &lds16[(bi)*4096 + c1*512]); \
    gl16(BT + (size_t)(n0 + sr0) * DM + (k0) + spc, &lds16[8192 + (bi)*4096 + c0*512]); \
    gl16(BT + (size_t)(n0 + sr1) * DM + (k0) + spc, &lds16[8192 + (bi)*4096 + c1*512]); \
  } while (0)

  STAGE(0, 0);
  __syncthreads();   // vmcnt(0) drain: buf0 ready
  for (int k0 = 0; k0 < DM; k0 += 32) {
    const int cur = (k0 >> 5) & 1;
    if (k0 + 32 < DM) STAGE(cur ^ 1, k0 + 32);   // issue next-tile loads FIRST
    s16x8 ah[4], bh[4];
#pragma unroll
    for (int i = 0; i < 4; ++i) {
      ah[i] = *(const s16x8*)&lds16[cur*4096 + (wr*64 + i*16 + lm) * 32 + lg*8];
      bh[i] = *(const s16x8*)&lds16[8192 + cur*4096 + (wc*64 + i*16 + lm) * 32 + lg*8];
    }
#pragma unroll
    for (int i = 0; i < 4; ++i)
#pragma unroll
      for (int j = 0; j < 4; ++j)
        acc[i][j] = __builtin_amdgcn_mfma_f32_16x16x32_bf16(ah[i], bh[j], acc[i][j], 0, 0, 0);
    __syncthreads();   // next buf staged (vmcnt0) AND cur reads done
  }
#undef STAGE

#pragma unroll
  for (int i = 0; i < 4; ++i)
#pragma unroll
    for (int j = 0; j < 4; ++j) {
      const int colg = n0 + wc*64 + j*16 + lm;
      const int rowb = m0 + wr*64 + i*16 + lg*4;
      const float bcol = bias[colg];
      if (mode == 0) {
#pragma unroll
        for (int r = 0; r < 4; ++r)
          out[(size_t)(rowb + r) * DM + colg] = f2bf(acc[i][j][r] + bcol);
      } else {  // vT transposed bf16
        const int bb = rowb >> 11, key = rowb & 2047;
        const int hh = colg >> 6, dv = colg & 63;
        s16x4 pk;
#pragma unroll
        for (int r = 0; r < 4; ++r) pk[r] = (short)f2bf(acc[i][j][r] + bcol);
        *(s16x4*)(out + (((size_t)bb*NH + hh)*HD + dv)*SLK + key) = pk;
      }
    }
}

// ---------------------------------------------------------------------------
// Flash attention (FROZEN round-11 build: 101us, VGPR 64). Base-2 softmax,
// deferred-max, cvt_pk P-store, per-lane l partials. DO NOT MODIFY:
// any VGPR increase past 64 drops occupancy 35->24% and costs ~20us
// (measured rounds 8, 9, 13, 16).
// ---------------------------------------------------------------------------
__global__ __launch_bounds__(256) void attn_mfma_k(
    const u16* __restrict__ qb, const u16* __restrict__ kb,
    const u16* __restrict__ vT, const u32* __restrict__ mbits,
    u16* __restrict__ wv, float* __restrict__ ml) {
  __shared__ u16 ks[64][72];
  __shared__ u16 vs[64][72];
  __shared__ u16 ps[4][16][72];
  const int qt = blockIdx.x, h = blockIdx.y, b = blockIdx.z;
  const int t = threadIdx.x, wid = t >> 6, lane = t & 63, lg = lane >> 4, lm = lane & 15;
  const int q0 = qt * 64, qw = q0 + wid * 16;
  s16x8 qh[2];
#pragma unroll
  for (int s = 0; s < 2; ++s) {
    size_t off = ((size_t)(b*SLQ + qw + lm)) * DM + h*HD + s*32 + lg*8;
    qh[s] = *(const s16x8*)(qb + off);
  }
  f32x4 O[4];
#pragma unroll
  for (int j = 0; j < 4; ++j) O[j] = (f32x4)(0.0f);
  float m_r[4] = {-INFINITY, -INFINITY, -INFINITY, -INFINITY};
  float l_r[4] = {0.f, 0.f, 0.f, 0.f};   // per-lane partials (16 lanes/row)
  const int srow = t >> 2, sch = t & 3;
  for (int j0 = 0; j0 < SLK; j0 += 64) {
    {
      size_t koff = ((size_t)(b*SLK + j0 + srow)) * DM + h*HD + sch*16;
      *(s16x8*)&ks[srow][sch*16]     = *(const s16x8*)(kb + koff);
      *(s16x8*)&ks[srow][sch*16 + 8] = *(const s16x8*)(kb + koff + 8);
      size_t voff = (((size_t)b*NH + h)*HD + srow)*SLK + j0 + sch*16;
      *(s16x8*)&vs[srow][sch*16]     = *(const s16x8*)(vT + voff);
      *(s16x8*)&vs[srow][sch*16 + 8] = *(const s16x8*)(vT + voff + 8);
    }
    __syncthreads();
    // QK^T
    f32x4 sc[4];
#pragma unroll
    for (int j = 0; j < 4; ++j) {
      s16x8 kh0 = *(const s16x8*)&ks[j*16 + lm][lg*8];
      s16x8 kh1 = *(const s16x8*)&ks[j*16 + lm][32 + lg*8];
      f32x4 c = (f32x4)(0.0f);
      c = __builtin_amdgcn_mfma_f32_16x16x32_bf16(qh[0], kh0, c, 0, 0, 0);
      c = __builtin_amdgcn_mfma_f32_16x16x32_bf16(qh[1], kh1, c, 0, 0, 0);
      sc[j] = c;
    }
    // mask + deferred-max base-2 softmax per q-row (reg r)
#pragma unroll
    for (int r = 0; r < 4; ++r) {
      size_t mrow = ((size_t)(b*SLQ + qw + lg*4 + r)) * (SLK/32) + (j0 >> 5);
      u32 w0 = mbits[mrow], w1 = mbits[mrow + 1];
      float sv[4];
#pragma unroll
      for (int j = 0; j < 4; ++j) {
        u32 w = (j < 2) ? w0 : w1;
        int bit = (w >> ((j*16 + lm) & 31)) & 1;
        sv[j] = bit ? sc[j][r] * C2 : -1e9f;
      }
      float pmax = fmaxf(fmaxf(sv[0], sv[1]), fmaxf(sv[2], sv[3]));
      if (!__all(pmax <= m_r[r] + 8.0f)) {       // slow path: rare
        float mx = pmax;
#pragma unroll
        for (int off = 1; off < 16; off <<= 1) mx = fmaxf(mx, __shfl_xor(mx, off, 64));
        float mnew  = fmaxf(m_r[r], mx);
        float alpha = EXP2(m_r[r] - mnew);       // m=-inf -> 0
        m_r[r] = mnew;
        l_r[r] *= alpha;
#pragma unroll
        for (int j = 0; j < 4; ++j) O[j][r] *= alpha;
      }
      float p0 = EXP2(sv[0] - m_r[r]);
      float p1 = EXP2(sv[1] - m_r[r]);
      float p2 = EXP2(sv[2] - m_r[r]);
      float p3 = EXP2(sv[3] - m_r[r]);
      l_r[r] += (p0 + p1) + (p2 + p3);
      u32 pk01 = cvtpk(p0, p1);
      u32 pk23 = cvtpk(p2, p3);
      ps[wid][lg*4 + r][0*16 + lm] = (u16)(pk01 & 0xffffu);
      ps[wid][lg*4 + r][1*16 + lm] = (u16)(pk01 >> 16);
      ps[wid][lg*4 + r][2*16 + lm] = (u16)(pk23 & 0xffffu);
      ps[wid][lg*4 + r][3*16 + lm] = (u16)(pk23 >> 16);
    }
    // PV
    {
      s16x8 pa0 = *(const s16x8*)&ps[wid][lm][lg*8];
      s16x8 pa1 = *(const s16x8*)&ps[wid][lm][32 + lg*8];
#pragma unroll
      for (int j = 0; j < 4; ++j) {
        s16x8 vb0 = *(const s16x8*)&vs[j*16 + lm][lg*8];
        s16x8 vb1 = *(const s16x8*)&vs[j*16 + lm][32 + lg*8];
        O[j] = __builtin_amdgcn_mfma_f32_16x16x32_bf16(pa0, vb0, O[j], 0, 0, 0);
        O[j] = __builtin_amdgcn_mfma_f32_16x16x32_bf16(pa1, vb1, O[j], 0, 0, 0);
      }
    }
    __syncthreads();
  }
  // final l reduction across the 16 lanes of each row (once)
#pragma unroll
  for (int r = 0; r < 4; ++r) {
#pragma unroll
    for (int off = 1; off < 16; off <<= 1) l_r[r] += __shfl_xor(l_r[r], off, 64);
  }
#pragma unroll
  for (int j = 0; j < 4; ++j)
#pragma unroll
    for (int r = 0; r < 4; ++r) {
      float v = O[j][r] / l_r[r];
      size_t row = (size_t)(b*SLQ + qw + lg*4 + r);
      wv[row*DM + h*HD + j*16 + lm] = f2bf(v);
    }
  if (lm == 0) {
#pragma unroll
    for (int r = 0; r < 4; ++r) {
      float* mp = ml + ((size_t)(b*NH + h)*SLQ + qw + lg*4 + r) * 2;
      mp[0] = m_r[r]; mp[1] = l_r[r];   // m in base-2 units
    }
  }
}

// ---------------------------------------------------------------------------
// tail_k: fused wmean + output projection (one launch, 2304 blocks):
//   [0,256)     gemm_o: out0 = wvb@WoT + bo (f32) -- dispatched first.
//   [256,2304)  wmean: one 64q x 64k tile; LDS-staged K with DOUBLE BUFFER
//               across the h-loop (stage h+1 while computing h; ONE barrier
//               per head). Bitwise-identical accumulation order.
// LDS: 9216 u16 = 18 KB (gemm_o uses 8192 u16; wmean dbuf uses 9216).
// ---------------------------------------------------------------------------
__global__ __launch_bounds__(256) void tail_k(
    const u16* __restrict__ qb, const u16* __restrict__ kb,
    const u32* __restrict__ mbits, const float* __restrict__ ml,
    float* __restrict__ out1,
    const u16* __restrict__ wvb, const u16* __restrict__ WoT,
    const float* __restrict__ bo, float* __restrict__ out0) {
  __shared__ u16 lds[9216];   // 18 KB
  const int gid = blockIdx.x, t = threadIdx.x;
  const int wid = t >> 6, lane = t & 63, lg = lane >> 4, lm = lane & 15;

  if (gid < 256) {
    // ---- output projection ----
    u16* Ah = lds;
    u16* Bh = lds + 128 * 32;
    const int m0 = (gid >> 3) * 128, n0 = (gid & 7) * 128;
    const int wr = wid >> 1, wc = wid & 1;
    f32x4 acc[4][4];
#pragma unroll
    for (int i = 0; i < 4; ++i)
#pragma unroll
      for (int j = 0; j < 4; ++j) acc[i][j] = (f32x4)(0.0f);
    const int c0 = wid * 2, c1 = wid * 2 + 1;
    const int sr0 = c0 * 16 + (lane >> 2), sr1 = c1 * 16 + (lane >> 2);
    const int spc = (lane & 3) * 8;
    for (int k0 = 0; k0 < DM; k0 += 32) {
      gl16(wvb + (size_t)(m0 + sr0) * DM + k0 + spc, &Ah[c0 * 512]);
      gl16(wvb + (size_t)(m0 + sr1) * DM + k0 + spc, &Ah[c1 * 512]);
      gl16(WoT + (size_t)(n0 + sr0) * DM + k0 + spc, &Bh[c0 * 512]);
      gl16(WoT + (size_t)(n0 + sr1) * DM + k0 + spc, &Bh[c1 * 512]);
      __syncthreads();
      s16x8 ah[4], bh[4];
#pragma unroll
      for (int i = 0; i < 4; ++i) {
        ah[i] = *(const s16x8*)&Ah[(wr*64 + i*16 + lm) * 32 + lg*8];
        bh[i] = *(const s16x8*)&Bh[(wc*64 + i*16 + lm) * 32 + lg*8];
      }
#pragma unroll
      for (int i = 0; i < 4; ++i)
#pragma unroll
        for (int j = 0; j < 4; ++j)
          acc[i][j] = __builtin_amdgcn_mfma_f32_16x16x32_bf16(ah[i], bh[j], acc[i][j], 0, 0, 0);
      __syncthreads();
    }
#pragma unroll
    for (int i = 0; i < 4; ++i)
#pragma unroll
      for (int j = 0; j < 4; ++j) {
        const int colg = n0 + wc*64 + j*16 + lm;
        const int rowb = m0 + wr*64 + i*16 + lg*4;
        const float bcol = bo[colg];
#pragma unroll
        for (int r = 0; r < 4; ++r)
          out0[(size_t)(rowb + r) * DM + colg] = acc[i][j][r] + bcol;
      }
  } else {
    // ---- weight_mean tile: double-buffered K staging across heads ----
    u16 (*ks)[72] = (u16(*)[72])lds;   // rows [0,64)=buf0, [64,128)=buf1
    const int g = gid - 256;
    const int j0 = (g & 31) * 64, q0 = ((g >> 5) & 15) * 64, b = g >> 9;
    const int qw = q0 + wid * 16;
    const int srow = t >> 2, sch = t & 3;
    f32x4 wm[4];
#pragma unroll
    for (int j = 0; j < 4; ++j) wm[j] = (f32x4)(0.0f);
    u32 w0[4], w1[4];
#pragma unroll
    for (int r = 0; r < 4; ++r) {
      size_t mrow = ((size_t)(b*SLQ + qw + lg*4 + r)) * (SLK/32) + (j0 >> 5);
      w0[r] = mbits[mrow]; w1[r] = mbits[mrow + 1];
    }
    // stage head 0 into buf0
    {
      size_t koff = ((size_t)(b*SLK + j0 + srow)) * DM + 0*HD + sch*16;
      *(s16x8*)&ks[srow][sch*16]     = *(const s16x8*)(kb + koff);
      *(s16x8*)&ks[srow][sch*16 + 8] = *(const s16x8*)(kb + koff + 8);
    }
    __syncthreads();
    for (int h = 0; h < NH; ++h) {
      const int cur = h & 1;
      if (h + 1 < NH) {   // stage next head into the other buffer
        const int nxt = cur ^ 1;
        size_t koff = ((size_t)(b*SLK + j0 + srow)) * DM + (h+1)*HD + sch*16;
        *(s16x8*)&ks[nxt*64 + srow][sch*16]     = *(const s16x8*)(kb + koff);
        *(s16x8*)&ks[nxt*64 + srow][sch*16 + 8] = *(const s16x8*)(kb + koff + 8);
      }
      s16x8 qh0, qh1;
      {
        size_t off = ((size_t)(b*SLQ + qw + lm)) * DM + h*HD + lg*8;
        qh0 = *(const s16x8*)(qb + off);
        qh1 = *(const s16x8*)(qb + off + 32);
      }
      float mr[4], li[4];
#pragma unroll
      for (int r = 0; r < 4; ++r) {
        const float* mp = ml + ((size_t)(b*NH + h)*SLQ + qw + lg*4 + r) * 2;
        mr[r] = mp[0]; li[r] = 1.0f / mp[1];
      }
#pragma unroll
      for (int j = 0; j < 4; ++j) {
        s16x8 kh0 = *(const s16x8*)&ks[cur*64 + j*16 + lm][lg*8];
        s16x8 kh1 = *(const s16x8*)&ks[cur*64 + j*16 + lm][32 + lg*8];
        f32x4 c = (f32x4)(0.0f);
        c = __builtin_amdgcn_mfma_f32_16x16x32_bf16(qh0, kh0, c, 0, 0, 0);
        c = __builtin_amdgcn_mfma_f32_16x16x32_bf16(qh1, kh1, c, 0, 0, 0);
#pragma unroll
        for (int r = 0; r < 4; ++r) {
          u32 w = (j < 2) ? w0[r] : w1[r];
          int bit = (w >> ((j*16 + lm) & 31)) & 1;
          float wvv = bit ? EXP2(__builtin_fmaf(c[r], C2, -mr[r])) * li[r] : 0.f;
          wm[j][r] += wvv;
        }
      }
      __syncthreads();  // next-head staging complete; cur reads done
    }
#pragma unroll
    for (int j = 0; j < 4; ++j)
#pragma unroll
      for (int r = 0; r < 4; ++r)
        out1[((size_t)b*SLQ + qw + lg*4 + r) * SLK + j0 + j*16 + lm]
            = wm[j][r] * (1.0f / NH);
  }
}

// ---------------------------------------------------------------------------
extern "C" void kernel_launch(void* const* d_in, const int* in_sizes, int n_in,
                              void* d_out, int out_size, void* d_ws, size_t ws_size,
                              hipStream_t stream) {
  const float* mq    = (const float*)d_in[0];
  const float* reply = (const float*)d_in[1];
  const int*   maskp = (const int*)  d_in[2];
  const float* Wq = (const float*)d_in[3];
  const float* bq = (const float*)d_in[4];
  const float* Wk = (const float*)d_in[5];
  const float* bk = (const float*)d_in[6];
  const float* Wv = (const float*)d_in[7];
  const float* bv = (const float*)d_in[8];
  const float* Wo = (const float*)d_in[9];
  const float* bo = (const float*)d_in[10];

  float* out0 = (float*)d_out;
  float* out1 = out0 + (size_t)NB*SLQ*DM;

  // workspace carve -- total ~82 MB
  char* w = (char*)d_ws;
  auto carve = [&](size_t bytes) { char* p = w; w += bytes; return p; };
  u16* WqT = (u16*)carve((size_t)DM*DM*2);
  u16* WkT = (u16*)carve((size_t)DM*DM*2);
  u16* WvT = (u16*)carve((size_t)DM*DM*2);
  u16* WoT = (u16*)carve((size_t)DM*DM*2);
  u16* mqb = (u16*)carve((size_t)NB*SLQ*DM*2);
  u16* rpb = (u16*)carve((size_t)NB*SLK*DM*2);
  u16* qbf = (u16*)carve((size_t)NB*SLQ*DM*2);
  u16* kbf = (u16*)carve((size_t)NB*SLK*DM*2);
  u16* vT  = (u16*)carve((size_t)NB*SLK*DM*2);
  u16* wvb = (u16*)carve((size_t)NB*SLQ*DM*2);
  float* mlb = (float*)carve((size_t)NB*NH*SLQ*2*4);
  unsigned long long* mbits = (unsigned long long*)carve((size_t)NB*SLQ*SLK/8);

  // setup needed before proj: cvt(x2) + convT(Wq,Wk,Wv)
  prep_k<<<1536, 256, 0, stream>>>(
      mq, mqb, reply, rpb, Wq, Wk, Wv, WqT, WkT, WvT);

  // proj launch: maskbits + convT(Wo) (memory, hide under GEMMs) + q/k/v proj
  proj_gemm_k<<<1792, 256, 0, stream>>>(
      maskp, mbits, Wo, WoT,
      mqb, rpb, WqT, WkT, WvT, bq, bk, bv, qbf, kbf, vT);

  attn_mfma_k<<<dim3(SLQ/64, NH, NB), 256, 0, stream>>>(
      qbf, kbf, vT, (const u32*)mbits, wvb, mlb);

  // fused tail: output projection (256 blocks, first) + weight_mean (2048)
  tail_k<<<2304, 256, 0, stream>>>(
      qbf, kbf, (const u32*)mbits, mlb, out1, wvb, WoT, bo, out0);
}

// Round 19
// 248.794 us; speedup vs baseline: 1.2432x; 1.0036x over previous
//
#include <hip/hip_runtime.h>
#include <math.h>

#define NB   4
#define NH   16
#define SLQ  1024
#define SLK  2048
#define DM   1024
#define HD   64

typedef __attribute__((ext_vector_type(8))) short s16x8;
typedef __attribute__((ext_vector_type(4))) short s16x4;
typedef __attribute__((ext_vector_type(4))) float f32x4;
typedef unsigned short u16;
typedef unsigned int   u32;

#if defined(__has_builtin)
#if __has_builtin(__builtin_amdgcn_exp2f)
#define EXP2(x) __builtin_amdgcn_exp2f(x)
#else
#define EXP2(x) exp2f(x)
#endif
#else
#define EXP2(x) exp2f(x)
#endif

// 0.125 * log2(e): scores scaled to base-2 inside attn/wmean
#define C2 0.18033688011116012f

__device__ inline u16 f2bf(float f) {
  u32 u = __float_as_uint(f);
  u32 r = u + 0x7fffu + ((u >> 16) & 1u);
  return (u16)(r >> 16);
}
__device__ inline float bf2f(u16 h) { return __uint_as_float(((u32)h) << 16); }

// pack 2 f32 -> 2 bf16 (RNE), lo = a, hi = b
__device__ __forceinline__ u32 cvtpk(float a, float b) {
  u32 r;
  asm("v_cvt_pk_bf16_f32 %0, %1, %2" : "=v"(r) : "v"(a), "v"(b));
  return r;
}

// async global->LDS, 16B per lane; LDS dest must be wave-uniform base.
__device__ __forceinline__ void gl16(const void* g, void* l) {
  __builtin_amdgcn_global_load_lds(
      (const __attribute__((address_space(1))) unsigned int*)g,
      (__attribute__((address_space(3))) unsigned int*)l, 16, 0, 0);
}

// shared convT tile body: W[64x64 tile] f32 -> T[n][k] bf16 (transposed)
__device__ __forceinline__ void convT_tile(
    const float* __restrict__ W, u16* __restrict__ T,
    float (*ts)[68], int cx, int ry, int t) {
  const int r0 = ry * 64, c0 = cx * 64;
  const int rr = t >> 4, cc = t & 15;
#pragma unroll
  for (int p = 0; p < 4; ++p) {
    float4 v = *(const float4*)(W + (size_t)(r0 + rr + p*16) * DM + c0 + cc*4);
    *(float4*)&ts[rr + p*16][cc*4] = v;
  }
  __syncthreads();
  const int c = t >> 2, ch = t & 3;
  s16x8 h0, h1;
#pragma unroll
  for (int i = 0; i < 8; ++i) {
    h0[i] = (short)f2bf(ts[ch*16 + i][c]);
    h1[i] = (short)f2bf(ts[ch*16 + 8 + i][c]);
  }
  size_t base = (size_t)(c0 + c) * DM + r0 + ch*16;
  *(s16x8*)(T + base) = h0; *(s16x8*)(T + base + 8) = h1;
}

// ---------------------------------------------------------------------------
// prep_k: setup needed BEFORE proj: 1536 blocks by range:
//   [0,768)    f32 -> bf16 for mq and reply (grid-stride)
//   [768,1536) 3x W{q,k,v} -> WT bf16 (tile per block)
// ---------------------------------------------------------------------------
__global__ __launch_bounds__(256) void prep_k(
    const float* __restrict__ mq, u16* __restrict__ mqb,
    const float* __restrict__ reply, u16* __restrict__ rpb,
    const float* __restrict__ W0, const float* __restrict__ W1,
    const float* __restrict__ W2,
    u16* __restrict__ T0, u16* __restrict__ T1, u16* __restrict__ T2) {
  __shared__ float ts[64][68];
  const int gid = blockIdx.x, t = threadIdx.x;
  if (gid < 768) {
    const int na = NB*SLQ*DM, nb = NB*SLK*DM;
    const int stride = 768 * 256 * 8;
    for (int i = (gid * 256 + t) * 8; i < na + nb; i += stride) {
      const float* s; u16* d; int off;
      if (i < na) { s = mq; d = mqb; off = i; } else { s = reply; d = rpb; off = i - na; }
      float4 x = *(const float4*)(s + off);
      float4 y = *(const float4*)(s + off + 4);
      s16x8 o;
      o[0] = (short)f2bf(x.x); o[1] = (short)f2bf(x.y);
      o[2] = (short)f2bf(x.z); o[3] = (short)f2bf(x.w);
      o[4] = (short)f2bf(y.x); o[5] = (short)f2bf(y.y);
      o[6] = (short)f2bf(y.z); o[7] = (short)f2bf(y.w);
      *(s16x8*)(d + off) = o;
    }
  } else {
    const int g = gid - 768;
    const int cx = g & 15, ry = (g >> 4) & 15, wz = g >> 8;   // wz 0..2
    const float* W = (wz == 0) ? W0 : (wz == 1) ? W1 : W2;
    u16* T        = (wz == 0) ? T0 : (wz == 1) ? T1 : T2;
    convT_tile(W, T, ts, cx, ry, t);
  }
}

// ---------------------------------------------------------------------------
// proj_gemm_k: 1792 blocks by range:
//   [0,256)    maskbits (grid-stride ballot)            -- memory, early
//   [256,512)  convT of Wo -> WoT                        -- memory, early
//   [512,1792) GEMM blocks, XCD-CHUNK-SWIZZLED (T1): hardware round-robins
//              blockIdx across 8 XCDs, so gs = (g&7)*160 + (g>>3) gives each
//              XCD a CONTIGUOUS run of geometry indices -> the 16 blocks
//              sharing an A-panel land on the same XCD's L2 (nwg=1280,
//              1280%8==0 -> bijective).
//              gs<256: q-proj; else k/v INTERLEAVED pairs sharing A-tiles.
// GEMM branch: T3-minimum 2-phase pipeline (dbuf LDS, STAGE(next) before
// frag-reads+MFMA, one barrier per K-step).
// ---------------------------------------------------------------------------
__global__ __launch_bounds__(256) void proj_gemm_k(
    const int* __restrict__ mask, unsigned long long* __restrict__ bits,
    const float* __restrict__ Wo, u16* __restrict__ WoT,
    const u16* __restrict__ mqb, const u16* __restrict__ rpb,
    const u16* __restrict__ WqT, const u16* __restrict__ WkT,
    const u16* __restrict__ WvT,
    const float* __restrict__ bq, const float* __restrict__ bk,
    const float* __restrict__ bv,
    u16* __restrict__ qbf, u16* __restrict__ kbf, u16* __restrict__ vTp) {
  __shared__ char ldsraw[32768];   // 32 KB: 2x(Ah+Bh) dbuf; convT uses 17.4 KB
  const int gid = blockIdx.x, t = threadIdx.x;

  if (gid < 256) {
    // ---- maskbits ----
    const int nwords = NB*SLQ*SLK/64;
    int gw   = (gid * 256 + t) >> 6;
    int lane = t & 63;
    const int nw = (256 * 256) >> 6;   // 1024 waves
    for (int w = gw; w < nwords; w += nw) {
      int m = mask[(size_t)w * 64 + lane];
      unsigned long long b = __ballot(m != 0);
      if (lane == 0) bits[w] = b;
    }
    return;
  }
  if (gid < 512) {
    // ---- convT of Wo ----
    const int g = gid - 256;
    convT_tile(Wo, WoT, (float(*)[68])ldsraw, g & 15, g >> 4, t);
    return;
  }

  // ---- GEMM branches (XCD-chunk swizzle over 1280 blocks) ----
  const int g  = gid - 512;                 // 0..1279
  const int gs = (g & 7) * 160 + (g >> 3);  // bijective chunked remap
  const u16* A; const u16* BT; const float* bias; u16* out;
  int mode, mt, nt;
  if (gs < 256) {
    A = mqb; BT = WqT; bias = bq; out = qbf; mode = 0;
    nt = gs & 7; mt = gs >> 3;
  } else {
    const int gk = gs - 256, pair = gk >> 1;
    nt = pair & 7; mt = pair >> 3;
    if ((gk & 1) == 0) { A = rpb; BT = WkT; bias = bk; out = kbf; mode = 0; }
    else               { A = rpb; BT = WvT; bias = bv; out = vTp; mode = 1; }
  }
  const int m0 = mt * 128, n0 = nt * 128;
  // dbuf layout: Ah[bi] at bi*4096, Bh[bi] at 8192 + bi*4096 (u16 units)
  u16* lds16 = (u16*)ldsraw;
  const int wid = t >> 6, lane = t & 63, lg = lane >> 4, lm = lane & 15;
  const int wr = wid >> 1, wc = wid & 1;
  f32x4 acc[4][4];
#pragma unroll
  for (int i = 0; i < 4; ++i)
#pragma unroll
    for (int j = 0; j < 4; ++j) acc[i][j] = (f32x4)(0.0f);

  const int c0 = wid * 2, c1 = wid * 2 + 1;
  const int sr0 = c0 * 16 + (lane >> 2), sr1 = c1 * 16 + (lane >> 2);
  const int spc = (lane & 3) * 8;

#define STAGE(bi, k0)                                                        \
  do {                                                                       \
    gl16(A  + (size_t)(m0 + sr0) * DM + (k0) + spc, &lds16[(bi)*4096 + c0*512]); \
    gl16(A  + (size_t)(m0 + sr1) * DM + (k0) + spc, &lds16[(bi)*4096 + c1*512]); \
    gl16(BT + (size_t)(n0 + sr0) * DM + (k0) + spc, &lds16[8192 + (bi)*4096 + c0*512]); \
    gl16(BT + (size_t)(n0 + sr1) * DM + (k0) + spc, &lds16[8192 + (bi)*4096 + c1*512]); \
  } while (0)

  STAGE(0, 0);
  __syncthreads();   // vmcnt(0) drain: buf0 ready
  for (int k0 = 0; k0 < DM; k0 += 32) {
    const int cur = (k0 >> 5) & 1;
    if (k0 + 32 < DM) STAGE(cur ^ 1, k0 + 32);   // issue next-tile loads FIRST
    s16x8 ah[4], bh[4];
#pragma unroll
    for (int i = 0; i < 4; ++i) {
      ah[i] = *(const s16x8*)&lds16[cur*4096 + (wr*64 + i*16 + lm) * 32 + lg*8];
      bh[i] = *(const s16x8*)&lds16[8192 + cur*4096 + (wc*64 + i*16 + lm) * 32 + lg*8];
    }
#pragma unroll
    for (int i = 0; i < 4; ++i)
#pragma unroll
      for (int j = 0; j < 4; ++j)
        acc[i][j] = __builtin_amdgcn_mfma_f32_16x16x32_bf16(ah[i], bh[j], acc[i][j], 0, 0, 0);
    __syncthreads();   // next buf staged (vmcnt0) AND cur reads done
  }
#undef STAGE

#pragma unroll
  for (int i = 0; i < 4; ++i)
#pragma unroll
    for (int j = 0; j < 4; ++j) {
      const int colg = n0 + wc*64 + j*16 + lm;
      const int rowb = m0 + wr*64 + i*16 + lg*4;
      const float bcol = bias[colg];
      if (mode == 0) {
#pragma unroll
        for (int r = 0; r < 4; ++r)
          out[(size_t)(rowb + r) * DM + colg] = f2bf(acc[i][j][r] + bcol);
      } else {  // vT transposed bf16
        const int bb = rowb >> 11, key = rowb & 2047;
        const int hh = colg >> 6, dv = colg & 63;
        s16x4 pk;
#pragma unroll
        for (int r = 0; r < 4; ++r) pk[r] = (short)f2bf(acc[i][j][r] + bcol);
        *(s16x4*)(out + (((size_t)bb*NH + hh)*HD + dv)*SLK + key) = pk;
      }
    }
}

// ---------------------------------------------------------------------------
// Flash attention (FROZEN round-11 build: 101us, VGPR 64). Base-2 softmax,
// deferred-max, cvt_pk P-store, per-lane l partials. DO NOT MODIFY:
// any VGPR increase past 64 drops occupancy 35->24% and costs ~20us
// (measured rounds 8, 9, 13, 16).
// ---------------------------------------------------------------------------
__global__ __launch_bounds__(256) void attn_mfma_k(
    const u16* __restrict__ qb, const u16* __restrict__ kb,
    const u16* __restrict__ vT, const u32* __restrict__ mbits,
    u16* __restrict__ wv, float* __restrict__ ml) {
  __shared__ u16 ks[64][72];
  __shared__ u16 vs[64][72];
  __shared__ u16 ps[4][16][72];
  const int qt = blockIdx.x, h = blockIdx.y, b = blockIdx.z;
  const int t = threadIdx.x, wid = t >> 6, lane = t & 63, lg = lane >> 4, lm = lane & 15;
  const int q0 = qt * 64, qw = q0 + wid * 16;
  s16x8 qh[2];
#pragma unroll
  for (int s = 0; s < 2; ++s) {
    size_t off = ((size_t)(b*SLQ + qw + lm)) * DM + h*HD + s*32 + lg*8;
    qh[s] = *(const s16x8*)(qb + off);
  }
  f32x4 O[4];
#pragma unroll
  for (int j = 0; j < 4; ++j) O[j] = (f32x4)(0.0f);
  float m_r[4] = {-INFINITY, -INFINITY, -INFINITY, -INFINITY};
  float l_r[4] = {0.f, 0.f, 0.f, 0.f};   // per-lane partials (16 lanes/row)
  const int srow = t >> 2, sch = t & 3;
  for (int j0 = 0; j0 < SLK; j0 += 64) {
    {
      size_t koff = ((size_t)(b*SLK + j0 + srow)) * DM + h*HD + sch*16;
      *(s16x8*)&ks[srow][sch*16]     = *(const s16x8*)(kb + koff);
      *(s16x8*)&ks[srow][sch*16 + 8] = *(const s16x8*)(kb + koff + 8);
      size_t voff = (((size_t)b*NH + h)*HD + srow)*SLK + j0 + sch*16;
      *(s16x8*)&vs[srow][sch*16]     = *(const s16x8*)(vT + voff);
      *(s16x8*)&vs[srow][sch*16 + 8] = *(const s16x8*)(vT + voff + 8);
    }
    __syncthreads();
    // QK^T
    f32x4 sc[4];
#pragma unroll
    for (int j = 0; j < 4; ++j) {
      s16x8 kh0 = *(const s16x8*)&ks[j*16 + lm][lg*8];
      s16x8 kh1 = *(const s16x8*)&ks[j*16 + lm][32 + lg*8];
      f32x4 c = (f32x4)(0.0f);
      c = __builtin_amdgcn_mfma_f32_16x16x32_bf16(qh[0], kh0, c, 0, 0, 0);
      c = __builtin_amdgcn_mfma_f32_16x16x32_bf16(qh[1], kh1, c, 0, 0, 0);
      sc[j] = c;
    }
    // mask + deferred-max base-2 softmax per q-row (reg r)
#pragma unroll
    for (int r = 0; r < 4; ++r) {
      size_t mrow = ((size_t)(b*SLQ + qw + lg*4 + r)) * (SLK/32) + (j0 >> 5);
      u32 w0 = mbits[mrow], w1 = mbits[mrow + 1];
      float sv[4];
#pragma unroll
      for (int j = 0; j < 4; ++j) {
        u32 w = (j < 2) ? w0 : w1;
        int bit = (w >> ((j*16 + lm) & 31)) & 1;
        sv[j] = bit ? sc[j][r] * C2 : -1e9f;
      }
      float pmax = fmaxf(fmaxf(sv[0], sv[1]), fmaxf(sv[2], sv[3]));
      if (!__all(pmax <= m_r[r] + 8.0f)) {       // slow path: rare
        float mx = pmax;
#pragma unroll
        for (int off = 1; off < 16; off <<= 1) mx = fmaxf(mx, __shfl_xor(mx, off, 64));
        float mnew  = fmaxf(m_r[r], mx);
        float alpha = EXP2(m_r[r] - mnew);       // m=-inf -> 0
        m_r[r] = mnew;
        l_r[r] *= alpha;
#pragma unroll
        for (int j = 0; j < 4; ++j) O[j][r] *= alpha;
      }
      float p0 = EXP2(sv[0] - m_r[r]);
      float p1 = EXP2(sv[1] - m_r[r]);
      float p2 = EXP2(sv[2] - m_r[r]);
      float p3 = EXP2(sv[3] - m_r[r]);
      l_r[r] += (p0 + p1) + (p2 + p3);
      u32 pk01 = cvtpk(p0, p1);
      u32 pk23 = cvtpk(p2, p3);
      ps[wid][lg*4 + r][0*16 + lm] = (u16)(pk01 & 0xffffu);
      ps[wid][lg*4 + r][1*16 + lm] = (u16)(pk01 >> 16);
      ps[wid][lg*4 + r][2*16 + lm] = (u16)(pk23 & 0xffffu);
      ps[wid][lg*4 + r][3*16 + lm] = (u16)(pk23 >> 16);
    }
    // PV
    {
      s16x8 pa0 = *(const s16x8*)&ps[wid][lm][lg*8];
      s16x8 pa1 = *(const s16x8*)&ps[wid][lm][32 + lg*8];
#pragma unroll
      for (int j = 0; j < 4; ++j) {
        s16x8 vb0 = *(const s16x8*)&vs[j*16 + lm][lg*8];
        s16x8 vb1 = *(const s16x8*)&vs[j*16 + lm][32 + lg*8];
        O[j] = __builtin_amdgcn_mfma_f32_16x16x32_bf16(pa0, vb0, O[j], 0, 0, 0);
        O[j] = __builtin_amdgcn_mfma_f32_16x16x32_bf16(pa1, vb1, O[j], 0, 0, 0);
      }
    }
    __syncthreads();
  }
  // final l reduction across the 16 lanes of each row (once)
#pragma unroll
  for (int r = 0; r < 4; ++r) {
#pragma unroll
    for (int off = 1; off < 16; off <<= 1) l_r[r] += __shfl_xor(l_r[r], off, 64);
  }
#pragma unroll
  for (int j = 0; j < 4; ++j)
#pragma unroll
    for (int r = 0; r < 4; ++r) {
      float v = O[j][r] / l_r[r];
      size_t row = (size_t)(b*SLQ + qw + lg*4 + r);
      wv[row*DM + h*HD + j*16 + lm] = f2bf(v);
    }
  if (lm == 0) {
#pragma unroll
    for (int r = 0; r < 4; ++r) {
      float* mp = ml + ((size_t)(b*NH + h)*SLQ + qw + lg*4 + r) * 2;
      mp[0] = m_r[r]; mp[1] = l_r[r];   // m in base-2 units
    }
  }
}

// ---------------------------------------------------------------------------
// tail_k: fused wmean + output projection (one launch, 2304 blocks):
//   [0,256)     gemm_o: out0 = wvb@WoT + bo (f32) -- dispatched first.
//   [256,2304)  wmean: one 64q x 64k tile; LDS-staged K with DOUBLE BUFFER
//               across the h-loop (stage h+1 while computing h; ONE barrier
//               per head). Bitwise-identical accumulation order.
// LDS: 9216 u16 = 18 KB (gemm_o uses 8192 u16; wmean dbuf uses 9216).
// ---------------------------------------------------------------------------
__global__ __launch_bounds__(256) void tail_k(
    const u16* __restrict__ qb, const u16* __restrict__ kb,
    const u32* __restrict__ mbits, const float* __restrict__ ml,
    float* __restrict__ out1,
    const u16* __restrict__ wvb, const u16* __restrict__ WoT,
    const float* __restrict__ bo, float* __restrict__ out0) {
  __shared__ u16 lds[9216];   // 18 KB
  const int gid = blockIdx.x, t = threadIdx.x;
  const int wid = t >> 6, lane = t & 63, lg = lane >> 4, lm = lane & 15;

  if (gid < 256) {
    // ---- output projection ----
    u16* Ah = lds;
    u16* Bh = lds + 128 * 32;
    const int m0 = (gid >> 3) * 128, n0 = (gid & 7) * 128;
    const int wr = wid >> 1, wc = wid & 1;
    f32x4 acc[4][4];
#pragma unroll
    for (int i = 0; i < 4; ++i)
#pragma unroll
      for (int j = 0; j < 4; ++j) acc[i][j] = (f32x4)(0.0f);
    const int c0 = wid * 2, c1 = wid * 2 + 1;
    const int sr0 = c0 * 16 + (lane >> 2), sr1 = c1 * 16 + (lane >> 2);
    const int spc = (lane & 3) * 8;
    for (int k0 = 0; k0 < DM; k0 += 32) {
      gl16(wvb + (size_t)(m0 + sr0) * DM + k0 + spc, &Ah[c0 * 512]);
      gl16(wvb + (size_t)(m0 + sr1) * DM + k0 + spc, &Ah[c1 * 512]);
      gl16(WoT + (size_t)(n0 + sr0) * DM + k0 + spc, &Bh[c0 * 512]);
      gl16(WoT + (size_t)(n0 + sr1) * DM + k0 + spc, &Bh[c1 * 512]);
      __syncthreads();
      s16x8 ah[4], bh[4];
#pragma unroll
      for (int i = 0; i < 4; ++i) {
        ah[i] = *(const s16x8*)&Ah[(wr*64 + i*16 + lm) * 32 + lg*8];
        bh[i] = *(const s16x8*)&Bh[(wc*64 + i*16 + lm) * 32 + lg*8];
      }
#pragma unroll
      for (int i = 0; i < 4; ++i)
#pragma unroll
        for (int j = 0; j < 4; ++j)
          acc[i][j] = __builtin_amdgcn_mfma_f32_16x16x32_bf16(ah[i], bh[j], acc[i][j], 0, 0, 0);
      __syncthreads();
    }
#pragma unroll
    for (int i = 0; i < 4; ++i)
#pragma unroll
      for (int j = 0; j < 4; ++j) {
        const int colg = n0 + wc*64 + j*16 + lm;
        const int rowb = m0 + wr*64 + i*16 + lg*4;
        const float bcol = bo[colg];
#pragma unroll
        for (int r = 0; r < 4; ++r)
          out0[(size_t)(rowb + r) * DM + colg] = acc[i][j][r] + bcol;
      }
  } else {
    // ---- weight_mean tile: double-buffered K staging across heads ----
    u16 (*ks)[72] = (u16(*)[72])lds;   // rows [0,64)=buf0, [64,128)=buf1
    const int g = gid - 256;
    const int j0 = (g & 31) * 64, q0 = ((g >> 5) & 15) * 64, b = g >> 9;
    const int qw = q0 + wid * 16;
    const int srow = t >> 2, sch = t & 3;
    f32x4 wm[4];
#pragma unroll
    for (int j = 0; j < 4; ++j) wm[j] = (f32x4)(0.0f);
    u32 w0[4], w1[4];
#pragma unroll
    for (int r = 0; r < 4; ++r) {
      size_t mrow = ((size_t)(b*SLQ + qw + lg*4 + r)) * (SLK/32) + (j0 >> 5);
      w0[r] = mbits[mrow]; w1[r] = mbits[mrow + 1];
    }
    // stage head 0 into buf0
    {
      size_t koff = ((size_t)(b*SLK + j0 + srow)) * DM + 0*HD + sch*16;
      *(s16x8*)&ks[srow][sch*16]     = *(const s16x8*)(kb + koff);
      *(s16x8*)&ks[srow][sch*16 + 8] = *(const s16x8*)(kb + koff + 8);
    }
    __syncthreads();
    for (int h = 0; h < NH; ++h) {
      const int cur = h & 1;
      if (h + 1 < NH) {   // stage next head into the other buffer
        const int nxt = cur ^ 1;
        size_t koff = ((size_t)(b*SLK + j0 + srow)) * DM + (h+1)*HD + sch*16;
        *(s16x8*)&ks[nxt*64 + srow][sch*16]     = *(const s16x8*)(kb + koff);
        *(s16x8*)&ks[nxt*64 + srow][sch*16 + 8] = *(const s16x8*)(kb + koff + 8);
      }
      s16x8 qh0, qh1;
      {
        size_t off = ((size_t)(b*SLQ + qw + lm)) * DM + h*HD + lg*8;
        qh0 = *(const s16x8*)(qb + off);
        qh1 = *(const s16x8*)(qb + off + 32);
      }
      float mr[4], li[4];
#pragma unroll
      for (int r = 0; r < 4; ++r) {
        const float* mp = ml + ((size_t)(b*NH + h)*SLQ + qw + lg*4 + r) * 2;
        mr[r] = mp[0]; li[r] = 1.0f / mp[1];
      }
#pragma unroll
      for (int j = 0; j < 4; ++j) {
        s16x8 kh0 = *(const s16x8*)&ks[cur*64 + j*16 + lm][lg*8];
        s16x8 kh1 = *(const s16x8*)&ks[cur*64 + j*16 + lm][32 + lg*8];
        f32x4 c = (f32x4)(0.0f);
        c = __builtin_amdgcn_mfma_f32_16x16x32_bf16(qh0, kh0, c, 0, 0, 0);
        c = __builtin_amdgcn_mfma_f32_16x16x32_bf16(qh1, kh1, c, 0, 0, 0);
#pragma unroll
        for (int r = 0; r < 4; ++r) {
          u32 w = (j < 2) ? w0[r] : w1[r];
          int bit = (w >> ((j*16 + lm) & 31)) & 1;
          float wvv = bit ? EXP2(__builtin_fmaf(c[r], C2, -mr[r])) * li[r] : 0.f;
          wm[j][r] += wvv;
        }
      }
      __syncthreads();  // next-head staging complete; cur reads done
    }
#pragma unroll
    for (int j = 0; j < 4; ++j)
#pragma unroll
      for (int r = 0; r < 4; ++r)
        out1[((size_t)b*SLQ + qw + lg*4 + r) * SLK + j0 + j*16 + lm]
            = wm[j][r] * (1.0f / NH);
  }
}

// ---------------------------------------------------------------------------
extern "C" void kernel_launch(void* const* d_in, const int* in_sizes, int n_in,
                              void* d_out, int out_size, void* d_ws, size_t ws_size,
                              hipStream_t stream) {
  const float* mq    = (const float*)d_in[0];
  const float* reply = (const float*)d_in[1];
  const int*   maskp = (const int*)  d_in[2];
  const float* Wq = (const float*)d_in[3];
  const float* bq = (const float*)d_in[4];
  const float* Wk = (const float*)d_in[5];
  const float* bk = (const float*)d_in[6];
  const float* Wv = (const float*)d_in[7];
  const float* bv = (const float*)d_in[8];
  const float* Wo = (const float*)d_in[9];
  const float* bo = (const float*)d_in[10];

  float* out0 = (float*)d_out;
  float* out1 = out0 + (size_t)NB*SLQ*DM;

  // workspace carve -- total ~82 MB
  char* w = (char*)d_ws;
  auto carve = [&](size_t bytes) { char* p = w; w += bytes; return p; };
  u16* WqT = (u16*)carve((size_t)DM*DM*2);
  u16* WkT = (u16*)carve((size_t)DM*DM*2);
  u16* WvT = (u16*)carve((size_t)DM*DM*2);
  u16* WoT = (u16*)carve((size_t)DM*DM*2);
  u16* mqb = (u16*)carve((size_t)NB*SLQ*DM*2);
  u16* rpb = (u16*)carve((size_t)NB*SLK*DM*2);
  u16* qbf = (u16*)carve((size_t)NB*SLQ*DM*2);
  u16* kbf = (u16*)carve((size_t)NB*SLK*DM*2);
  u16* vT  = (u16*)carve((size_t)NB*SLK*DM*2);
  u16* wvb = (u16*)carve((size_t)NB*SLQ*DM*2);
  float* mlb = (float*)carve((size_t)NB*NH*SLQ*2*4);
  unsigned long long* mbits = (unsigned long long*)carve((size_t)NB*SLQ*SLK/8);

  // setup needed before proj: cvt(x2) + convT(Wq,Wk,Wv)
  prep_k<<<1536, 256, 0, stream>>>(
      mq, mqb, reply, rpb, Wq, Wk, Wv, WqT, WkT, WvT);

  // proj launch: maskbits + convT(Wo) (hide under GEMMs) + swizzled q/k/v proj
  proj_gemm_k<<<1792, 256, 0, stream>>>(
      maskp, mbits, Wo, WoT,
      mqb, rpb, WqT, WkT, WvT, bq, bk, bv, qbf, kbf, vT);

  attn_mfma_k<<<dim3(SLQ/64, NH, NB), 256, 0, stream>>>(
      qbf, kbf, vT, (const u32*)mbits, wvb, mlb);

  // fused tail: output projection (256 blocks, first) + weight_mean (2048)
  tail_k<<<2304, 256, 0, stream>>>(
      qbf, kbf, (const u32*)mbits, mlb, out1, wvb, WoT, bo, out0);
}